// Round 19
// baseline (247.430 us; speedup 1.0000x reference)
//
#include <hip/hip_runtime.h>
#include <hip/hip_bf16.h>

typedef __attribute__((ext_vector_type(8))) short short8;
typedef __attribute__((ext_vector_type(16))) float f32x16;
typedef __attribute__((ext_vector_type(4))) float f32x4;
typedef __attribute__((ext_vector_type(4))) unsigned int uint4v;
typedef __attribute__((ext_vector_type(4))) unsigned short ushort4v;

__device__ __forceinline__ float silu_f(float v) {
    return v * __builtin_amdgcn_rcpf(1.0f + __expf(-v));
}
__device__ __forceinline__ unsigned short bfhi(float v) {
    __hip_bfloat16 h = __float2bfloat16(v);
    return *reinterpret_cast<unsigned short*>(&h);
}
__device__ __forceinline__ float bf2f(unsigned short u) {
    __hip_bfloat16 h;
    *reinterpret_cast<unsigned short*>(&h) = u;
    return __bfloat162float(h);
}

// ======= weight prep: f32 -> bf16 hi/lo fragments (pf*1024 + lane*8, lo +512)
__global__ __launch_bounds__(256) void prep_small(
    const float* __restrict__ w1, const float* __restrict__ wc0,
    const float* __restrict__ wb1, const float* __restrict__ wb2,
    const float* __restrict__ wc1, const float* __restrict__ w0,
    unsigned short* __restrict__ arena)
{
    const int u = blockIdx.x * 256 + threadIdx.x;   // 0..6015
    if (u >= 6016) return;
    const int lane = u & 63, pf = u >> 6;
    float wv[8];
    if (pf < 36) {
        const int q = pf, cc = q & 1, rnd = (q >> 1) & 1, tap = q >> 2;
        const int co = cc * 32 + (lane & 31), ci0 = rnd * 16 + (lane >> 5) * 8;
        #pragma unroll
        for (int j = 0; j < 8; ++j) wv[j] = w1[(co * 32 + ci0 + j) * 9 + tap];
    } else if (pf < 44) {
        const int q = pf - 36, cc = q & 1, rnd = q >> 1;
        const int co = cc * 32 + (lane & 31), ci0 = rnd * 16 + (lane >> 5) * 8;
        #pragma unroll
        for (int j = 0; j < 8; ++j) wv[j] = wc0[co * 64 + ci0 + j];
    } else if (pf < 62) {
        const int q = pf - 44, rnd = q & 1, tap = q >> 1;
        const int co = lane & 31, ci0 = rnd * 16 + (lane >> 5) * 8;
        #pragma unroll
        for (int j = 0; j < 8; ++j) wv[j] = wb1[(co * 32 + ci0 + j) * 9 + tap];
    } else if (pf < 80) {
        const int q = pf - 62, rnd = q & 1, tap = q >> 1;
        const int co = lane & 31, ci0 = rnd * 16 + (lane >> 5) * 8;
        #pragma unroll
        for (int j = 0; j < 8; ++j) wv[j] = wb2[(co * 32 + ci0 + j) * 9 + tap];
    } else if (pf < 92) {
        const int q = pf - 80, cc = q & 1, rnd = q >> 1;
        const int co = cc * 32 + (lane & 31), ci0 = rnd * 16 + (lane >> 5) * 8;
        #pragma unroll
        for (int j = 0; j < 8; ++j) wv[j] = wc1[co * 96 + ci0 + j];
    } else {
        const int co = lane & 31;
        const int k0 = (pf - 92) * 16 + (lane >> 5) * 8;
        #pragma unroll
        for (int j = 0; j < 8; ++j) {
            const int k = k0 + j;
            wv[j] = (k < 27) ? w0[(co * 3 + k / 9) * 9 + (k % 9)] : 0.0f;
        }
    }
    unsigned short hs[8], ls[8];
    #pragma unroll
    for (int j = 0; j < 8; ++j) {
        unsigned short hh = bfhi(wv[j]);
        hs[j] = hh; ls[j] = bfhi(wv[j] - bf2f(hh));
    }
    *reinterpret_cast<short8*>(&arena[pf * 1024 + lane * 8])       = *(short8*)hs;
    *reinterpret_cast<short8*>(&arena[pf * 1024 + 512 + lane * 8]) = *(short8*)ls;
}

// arena2 (in ws): w3, pf = ((cg*9+tap)*4 + rr)*2+cc, rr = ci/16. 144 pf
__global__ __launch_bounds__(256) void prep_w3(
    const float* __restrict__ w3, unsigned short* __restrict__ arena)
{
    const int u = blockIdx.x * 256 + threadIdx.x;   // 0..9215
    const int lane = u & 63, pf = u >> 6;
    const int cc = pf & 1, rr = (pf >> 1) & 3, t9 = pf >> 3;
    const int tap = t9 % 9, cg = t9 / 9;
    const int co = cg * 64 + cc * 32 + (lane & 31);
    const int ci0 = rr * 16 + (lane >> 5) * 8;
    unsigned short hs[8], ls[8];
    #pragma unroll
    for (int j = 0; j < 8; ++j) {
        float wv = w3[(co * 64 + ci0 + j) * 9 + tap];
        unsigned short hh = bfhi(wv);
        hs[j] = hh; ls[j] = bfhi(wv - bf2f(hh));
    }
    *reinterpret_cast<short8*>(&arena[pf * 1024 + lane * 8])       = *(short8*)hs;
    *reinterpret_cast<short8*>(&arena[pf * 1024 + 512 + lane * 8]) = *(short8*)ls;
}

// ---- stem phase-A helpers (325-rec 32x2 geometry, round-12/15 proven) -----
struct GDesc {
    int rc, Bsafe, Y, X;
    bool validR, valid, fastw;
};

__device__ __forceinline__ GDesc stem_desc(int g, int p, int ox0, int oy0) {
    GDesc d;
    d.rc = g * 32 + p;
    d.validR = d.rc < 325;
    const int rec_c = d.validR ? d.rc : 324;
    int gp, row, col;
    if (rec_c < 64)       { gp = 0; row = rec_c >> 5; col = rec_c & 31; }
    else if (rec_c < 130) { gp = 1; int r2 = rec_c - 64;  row = r2 / 33; col = r2 - row * 33; }
    else if (rec_c < 226) { gp = 2; int r2 = rec_c - 130; row = r2 >> 5; col = r2 & 31; }
    else                  { gp = 3; int r2 = rec_c - 226; row = r2 / 33; col = r2 - row * 33; }
    const int gr = (gp >= 2) ? oy0 - 1 + row : oy0 + row;
    const int gc = (gp & 1)  ? ox0 - 1 + col : ox0 + col;
    d.valid = d.validR && ((unsigned)gr < 160u) && ((unsigned)gc < 160u);
    d.Y = 2 * gr + (gp >> 1);
    d.X = 2 * gc + (gp & 1);
    d.Bsafe = d.valid ? (1280 * d.Y + 2 * d.X) : 641;
    const bool interior = d.valid && gr > 0 && gr < 159 && gc > 0 && gc < 159;
    d.fastw = __all(interior);
    return d;
}

// clamped issue (border/tail groups) — unchanged numerics
__device__ __forceinline__ void stem_issue(
    int Bsafe, const int* doff, const float* __restrict__ xb, float* xv)
{
    #pragma unroll
    for (int idx = 0; idx < 16; ++idx) {
        int a = Bsafe + doff[idx];
        a = max(a, 0);
        a = min(a, 1228799);
        xv[idx] = xb[a];
    }
}

// unclamped issue (interior groups: fastw guarantees all addrs in-bounds)
__device__ __forceinline__ void stem_issue_fast(
    int Bsafe, const int* doff, const float* __restrict__ xb, float* xv)
{
    #pragma unroll
    for (int idx = 0; idx < 16; ++idx)
        xv[idx] = xb[Bsafe + doff[idx]];
}

__device__ __forceinline__ void stem_process(
    const GDesc& d, const float* xv, unsigned short* lds,
    const unsigned short* __restrict__ wfr, const float* __restrict__ b0,
    int h, int h8, int lane)
{
    f32x16 a0;
    #pragma unroll
    for (int q = 0; q < 4; ++q) {
        f32x4 b4 = *reinterpret_cast<const f32x4*>(&b0[q * 8 + 4 * h]);
        #pragma unroll
        for (int r2 = 0; r2 < 4; ++r2) a0[q * 4 + r2] = b4[r2];
    }

    #pragma unroll
    for (int rnd = 0; rnd < 2; ++rnd) {
        unsigned short hs[8], ls[8];
        if (d.fastw) {
            #pragma unroll
            for (int j = 0; j < 8; ++j) {
                float v = xv[rnd * 8 + j];
                if (rnd == 1 && j >= 3) v = (h == 0) ? v : 0.0f;
                unsigned short hh = bfhi(v);
                hs[j] = hh; ls[j] = bfhi(v - bf2f(hh));
            }
        } else {
            #pragma unroll
            for (int j = 0; j < 8; ++j) {
                const int k = rnd * 16 + h8 + j;
                const int ci = (k * 57) >> 9;
                const int tap = k - 9 * ci;
                const int dy = (tap * 11) >> 5, dx = tap - 3 * dy;
                const int iy = 2 * d.Y + dy - 1;
                const int ix = 2 * d.X + dx - 1;
                bool ok = d.valid && ((unsigned)iy < 640u) && ((unsigned)ix < 640u);
                if (rnd == 1 && j >= 3) ok = ok && (h == 0);
                float v = ok ? xv[rnd * 8 + j] : 0.0f;
                unsigned short hh = bfhi(v);
                hs[j] = hh; ls[j] = bfhi(v - bf2f(hh));
            }
        }
        short8 Bh = *(short8*)hs, Bl = *(short8*)ls;
        const unsigned short* fb = wfr + (92 + rnd) * 1024 + lane * 8;
        short8 Awh = *reinterpret_cast<const short8*>(fb);
        short8 Awl = *reinterpret_cast<const short8*>(fb + 512);
        a0 = __builtin_amdgcn_mfma_f32_32x32x16_bf16(Awh, Bh, a0, 0, 0, 0);
        a0 = __builtin_amdgcn_mfma_f32_32x32x16_bf16(Awh, Bl, a0, 0, 0, 0);
        a0 = __builtin_amdgcn_mfma_f32_32x32x16_bf16(Awl, Bh, a0, 0, 0, 0);
    }

    if (d.validR) {
        const int pm = d.rc & 7;
        #pragma unroll
        for (int q = 0; q < 4; ++q) {
            ushort4v hv, lv;
            #pragma unroll
            for (int r2 = 0; r2 < 4; ++r2) {
                float v = d.valid ? silu_f(a0[q * 4 + r2]) : 0.0f;
                unsigned short hh = bfhi(v);
                hv[r2] = hh; lv[r2] = bfhi(v - bf2f(hh));
            }
            *reinterpret_cast<ushort4v*>(&lds[d.rc * 64 + (((2 * q)     ^ pm) * 8) + 4 * h]) = hv;
            *reinterpret_cast<ushort4v*>(&lds[d.rc * 64 + (((2 * q + 1) ^ pm) * 8) + 4 * h]) = lv;
        }
    }
}

// ============ STEM: conv0 + conv1 + wc0, 256 thr, 32x2 tile, depth-1 pf =====
__global__ __launch_bounds__(256, 4) void stem_fused(
    const float* __restrict__ x, const unsigned short* __restrict__ wfr,
    const unsigned short* __restrict__ wc0fr, const float* __restrict__ b0,
    const float* __restrict__ bias, const float* __restrict__ bc0,
    unsigned short* __restrict__ ycl)
{
    __shared__ unsigned short lds[20800];        // 325 recs x 64 ush = 41.6 KB
    const int tid = threadIdx.x;
    const int wv = tid >> 6, lane = tid & 63;
    const int p = lane & 31, h = lane >> 5;
    const int r = wv >> 1, cc = wv & 1;
    const int bx = blockIdx.x % 5, by = blockIdx.x / 5;
    const int ox0 = bx * 32, oy0 = by * 2;
    const int n = blockIdx.z;
    const float* xb = x + (long)n * 1228800;

    const int h8 = h * 8;
    int doff[16];
    #pragma unroll
    for (int idx = 0; idx < 16; ++idx) {
        const int k = (idx >> 3) * 16 + h8 + (idx & 7);
        if (k < 27) {
            const int ci = (k * 57) >> 9;
            const int tap = k - 9 * ci;
            const int dy = (tap * 11) >> 5, dx = tap - 3 * dy;
            doff[idx] = ci * 409600 + (dy - 1) * 640 + (dx - 1);
        } else {
            doff[idx] = 0;
        }
    }

    // ---- phase A with depth-1 prefetch; interior groups use unclamped issue
    {
        GDesc d0 = stem_desc(wv, p, ox0, oy0);
        float xva[16];
        if (d0.fastw) stem_issue_fast(d0.Bsafe, doff, xb, xva);
        else          stem_issue(d0.Bsafe, doff, xb, xva);

        GDesc d1 = stem_desc(wv + 4, p, ox0, oy0);
        float xvb[16];
        if (d1.fastw) stem_issue_fast(d1.Bsafe, doff, xb, xvb);
        else          stem_issue(d1.Bsafe, doff, xb, xvb);

        stem_process(d0, xva, lds, wfr, b0, h, h8, lane);

        if (wv < 3) {
            GDesc d2 = stem_desc(wv + 8, p, ox0, oy0);
            if (d2.fastw) stem_issue_fast(d2.Bsafe, doff, xb, xva);
            else          stem_issue(d2.Bsafe, doff, xb, xva);
            stem_process(d1, xvb, lds, wfr, b0, h, h8, lane);
            stem_process(d2, xva, lds, wfr, b0, h, h8, lane);
        } else {
            stem_process(d1, xvb, lds, wfr, b0, h, h8, lane);
        }
    }
    __syncthreads();

    // ---- conv1 K-loop from LDS h0 tile (no staging, no barriers)
    f32x16 acc;
    #pragma unroll
    for (int q = 0; q < 4; ++q) {
        f32x4 b4 = *reinterpret_cast<const f32x4*>(&bias[cc * 32 + q * 8 + 4 * h]);
        #pragma unroll
        for (int r2 = 0; r2 < 4; ++r2) acc[q * 4 + r2] = b4[r2];
    }
    #pragma unroll
    for (int c = 0; c < 2; ++c) {
        #pragma unroll
        for (int tap = 0; tap < 9; ++tap) {
            const int dy = tap / 3 - 1, dx = tap % 3 - 1;
            const int ppy = dy & 1, ppx = dx & 1;
            const int toy = ppy ? ((dy == -1) ? 0 : 1) : 0;
            const int tox = ppx ? ((dx == -1) ? 0 : 1) : 0;
            const int gp = ppy * 2 + ppx;
            const int base = (gp == 0) ? 0 : (gp == 1) ? 64 : (gp == 2) ? 130 : 226;
            const int W = ppx ? 33 : 32;
            const int rec = base + (ppy ? (r + toy) : r) * W + (p + tox);
            const unsigned short* t = &lds[rec * 64];
            const int pm = rec & 7;
            short8 Bh = *reinterpret_cast<const short8*>(t + (((4 * c + 2 * h)     ^ pm) * 8));
            short8 Bl = *reinterpret_cast<const short8*>(t + (((4 * c + 2 * h + 1) ^ pm) * 8));
            const unsigned short* fb = wfr + ((tap * 2 + c) * 2 + cc) * 1024 + lane * 8;
            short8 Awh = *reinterpret_cast<const short8*>(fb);
            short8 Awl = *reinterpret_cast<const short8*>(fb + 512);
            acc = __builtin_amdgcn_mfma_f32_32x32x16_bf16(Awh, Bh, acc, 0, 0, 0);
            acc = __builtin_amdgcn_mfma_f32_32x32x16_bf16(Awh, Bl, acc, 0, 0, 0);
            acc = __builtin_amdgcn_mfma_f32_32x32x16_bf16(Awl, Bh, acc, 0, 0, 0);
        }
    }

    // ---- stage y = silu(conv1) to LDS (64 recs x 128 ush), aliases h0 tile
    __syncthreads();
    {
        const int rec2 = r * 32 + p;
        #pragma unroll
        for (int q = 0; q < 4; ++q) {
            ushort4v hv, lv;
            #pragma unroll
            for (int r2 = 0; r2 < 4; ++r2) {
                float v = silu_f(acc[q * 4 + r2]);
                unsigned short hh = bfhi(v);
                hv[r2] = hh; lv[r2] = bfhi(v - bf2f(hh));
            }
            const int lsh = (2 * (cc * 4 + q))     ^ (rec2 & 15);
            const int lsl = (2 * (cc * 4 + q) + 1) ^ (rec2 & 15);
            *reinterpret_cast<ushort4v*>(&lds[rec2 * 128 + lsh * 8 + 4 * h]) = hv;
            *reinterpret_cast<ushort4v*>(&lds[rec2 * 128 + lsl * 8 + 4 * h]) = lv;
        }
    }
    __syncthreads();

    // ---- wc0: 1x1 64->64 from LDS y-tile; wave owns cc output chunk
    f32x16 a2;
    #pragma unroll
    for (int q = 0; q < 4; ++q) {
        f32x4 b4 = *reinterpret_cast<const f32x4*>(&bc0[cc * 32 + q * 8 + 4 * h]);
        #pragma unroll
        for (int r2 = 0; r2 < 4; ++r2) a2[q * 4 + r2] = b4[r2];
    }
    {
        const int rec2 = r * 32 + p;
        #pragma unroll
        for (int rnd = 0; rnd < 4; ++rnd) {
            const int sh = (4 * rnd + 2 * h)     ^ (rec2 & 15);
            const int sl = (4 * rnd + 2 * h + 1) ^ (rec2 & 15);
            short8 Bh = *reinterpret_cast<const short8*>(&lds[rec2 * 128 + sh * 8]);
            short8 Bl = *reinterpret_cast<const short8*>(&lds[rec2 * 128 + sl * 8]);
            const unsigned short* fb = wc0fr + (rnd * 2 + cc) * 1024 + lane * 8;
            short8 Awh = *reinterpret_cast<const short8*>(fb);
            short8 Awl = *reinterpret_cast<const short8*>(fb + 512);
            a2 = __builtin_amdgcn_mfma_f32_32x32x16_bf16(Awh, Bh, a2, 0, 0, 0);
            a2 = __builtin_amdgcn_mfma_f32_32x32x16_bf16(Awh, Bl, a2, 0, 0, 0);
            a2 = __builtin_amdgcn_mfma_f32_32x32x16_bf16(Awl, Bh, a2, 0, 0, 0);
        }
    }

    const int oy = oy0 + r;
    unsigned short* op = ycl + ((long)n * 25600 + (long)oy * 160 + ox0 + p) * 128;
    #pragma unroll
    for (int q = 0; q < 4; ++q) {
        ushort4v hv, lv;
        #pragma unroll
        for (int r2 = 0; r2 < 4; ++r2) {
            float v = silu_f(a2[q * 4 + r2]);
            unsigned short hh = bfhi(v);
            hv[r2] = hh; lv[r2] = bfhi(v - bf2f(hh));
        }
        const int gq = cc * 4 + q;
        *reinterpret_cast<ushort4v*>(op + gq * 16 + 4 * h)     = hv;
        *reinterpret_cast<ushort4v*>(op + gq * 16 + 8 + 4 * h) = lv;
    }
}

// ============ wb1: 32->32 s1 3x3, tile-only LDS, frags from global ==========
__global__ __launch_bounds__(512, 4) void wb3x3(
    const unsigned short* __restrict__ in, int inRec, int inSlot0,
    const unsigned short* __restrict__ wfr, const float* __restrict__ bias,
    unsigned short* __restrict__ outb)
{
    __shared__ unsigned short lds[21760];        // tile 34x10 x 64 ush (43.5 KB)
    const int tid = threadIdx.x;
    const int wv = tid >> 6, lane = tid & 63;
    const int p = lane & 31, h = lane >> 5;
    const int bx = blockIdx.x % 5, by = blockIdx.x / 5;
    const int ox0 = bx * 32, oy0 = by * 8;
    const int n = blockIdx.z;

    for (int u = tid; u < 2720; u += 512) {      // tile 34x10, 8 slots/rec
        const int rec = u >> 3, s = u & 7;
        const int row = rec / 34, col = rec - row * 34;
        const int gr = oy0 - 1 + row, gc = ox0 - 1 + col;
        uint4v val = {0, 0, 0, 0};
        if (gr >= 0 && gr < 160 && gc >= 0 && gc < 160)
            val = *reinterpret_cast<const uint4v*>(
                in + ((long)n * 25600 + gr * 160 + gc) * inRec + (inSlot0 + s) * 8);
        *reinterpret_cast<uint4v*>(&lds[rec * 64 + ((s ^ (rec & 7)) * 8)]) = val;
    }

    f32x16 acc;
    #pragma unroll
    for (int q = 0; q < 4; ++q) {
        f32x4 b4 = *reinterpret_cast<const f32x4*>(&bias[q * 8 + 4 * h]);
        #pragma unroll
        for (int r = 0; r < 4; ++r) acc[q * 4 + r] = b4[r];
    }
    __syncthreads();

    #pragma unroll
    for (int tap = 0; tap < 9; ++tap) {
        const int dy = tap / 3 - 1, dx = tap % 3 - 1;
        const int rec = (wv + dy + 1) * 34 + (p + dx + 1);
        const unsigned short* t = &lds[rec * 64];
        short8 Bh[2], Bl[2];
        #pragma unroll
        for (int rnd = 0; rnd < 2; ++rnd) {
            Bh[rnd] = *reinterpret_cast<const short8*>(t + (((rnd*4 + 2*h)     ^ (rec & 7)) * 8));
            Bl[rnd] = *reinterpret_cast<const short8*>(t + (((rnd*4 + 2*h + 1) ^ (rec & 7)) * 8));
        }
        #pragma unroll
        for (int rnd = 0; rnd < 2; ++rnd) {
            const unsigned short* fb = wfr + (tap * 2 + rnd) * 1024 + lane * 8;
            short8 Awh = *reinterpret_cast<const short8*>(fb);
            short8 Awl = *reinterpret_cast<const short8*>(fb + 512);
            acc = __builtin_amdgcn_mfma_f32_32x32x16_bf16(Awh, Bh[rnd], acc, 0, 0, 0);
            acc = __builtin_amdgcn_mfma_f32_32x32x16_bf16(Awh, Bl[rnd], acc, 0, 0, 0);
            acc = __builtin_amdgcn_mfma_f32_32x32x16_bf16(Awl, Bh[rnd], acc, 0, 0, 0);
        }
    }

    const int oy = oy0 + wv;
    const long prow = (long)n * 25600 + (long)oy * 160 + ox0 + p;
    unsigned short* op = outb + prow * 64;
    #pragma unroll
    for (int q = 0; q < 4; ++q) {
        ushort4v hv, lv;
        #pragma unroll
        for (int r = 0; r < 4; ++r) {
            float v = silu_f(acc[q * 4 + r]);
            unsigned short hh = bfhi(v);
            hv[r] = hh; lv[r] = bfhi(v - bf2f(hh));
        }
        *reinterpret_cast<ushort4v*>(op + q * 16 + 4 * h)     = hv;
        *reinterpret_cast<ushort4v*>(op + q * 16 + 8 + 4 * h) = lv;
    }
}

// ============ wb2+wc1 FUSED: 3x3 32->32 (+resid) then 1x1 96->64 ============
__global__ __launch_bounds__(512, 4) void wb2_wc1(
    const unsigned short* __restrict__ b1cl, const unsigned short* __restrict__ ycl,
    const unsigned short* __restrict__ wfr2, const unsigned short* __restrict__ wfrc,
    const float* __restrict__ bb2, const float* __restrict__ bc1,
    unsigned short* __restrict__ h2p)
{
    __shared__ unsigned short lds[21760];        // 34x10 tile / 256x64 b-tile
    const int tid = threadIdx.x;
    const int wv = tid >> 6, lane = tid & 63;
    const int p = lane & 31, h = lane >> 5;
    const int bx = blockIdx.x % 5, by = blockIdx.x / 5;
    const int ox0 = bx * 32, oy0 = by * 8;
    const int n = blockIdx.z;

    for (int u = tid; u < 2720; u += 512) {
        const int rec = u >> 3, s = u & 7;
        const int row = rec / 34, col = rec - row * 34;
        const int gr = oy0 - 1 + row, gc = ox0 - 1 + col;
        uint4v val = {0, 0, 0, 0};
        if (gr >= 0 && gr < 160 && gc >= 0 && gc < 160)
            val = *reinterpret_cast<const uint4v*>(
                b1cl + ((long)n * 25600 + gr * 160 + gc) * 64 + s * 8);
        *reinterpret_cast<uint4v*>(&lds[rec * 64 + ((s ^ (rec & 7)) * 8)]) = val;
    }

    f32x16 acc;
    #pragma unroll
    for (int q = 0; q < 4; ++q) {
        f32x4 b4 = *reinterpret_cast<const f32x4*>(&bb2[q * 8 + 4 * h]);
        #pragma unroll
        for (int r = 0; r < 4; ++r) acc[q * 4 + r] = b4[r];
    }
    __syncthreads();

    #pragma unroll
    for (int tap = 0; tap < 9; ++tap) {
        const int dy = tap / 3 - 1, dx = tap % 3 - 1;
        const int rec = (wv + dy + 1) * 34 + (p + dx + 1);
        const unsigned short* t = &lds[rec * 64];
        short8 Bh[2], Bl[2];
        #pragma unroll
        for (int rnd = 0; rnd < 2; ++rnd) {
            Bh[rnd] = *reinterpret_cast<const short8*>(t + (((rnd*4 + 2*h)     ^ (rec & 7)) * 8));
            Bl[rnd] = *reinterpret_cast<const short8*>(t + (((rnd*4 + 2*h + 1) ^ (rec & 7)) * 8));
        }
        #pragma unroll
        for (int rnd = 0; rnd < 2; ++rnd) {
            const unsigned short* fb = wfr2 + (tap * 2 + rnd) * 1024 + lane * 8;
            short8 Awh = *reinterpret_cast<const short8*>(fb);
            short8 Awl = *reinterpret_cast<const short8*>(fb + 512);
            acc = __builtin_amdgcn_mfma_f32_32x32x16_bf16(Awh, Bh[rnd], acc, 0, 0, 0);
            acc = __builtin_amdgcn_mfma_f32_32x32x16_bf16(Awh, Bl[rnd], acc, 0, 0, 0);
            acc = __builtin_amdgcn_mfma_f32_32x32x16_bf16(Awl, Bh[rnd], acc, 0, 0, 0);
        }
    }

    const int oy = oy0 + wv;
    const long prow = (long)n * 25600 + (long)oy * 160 + ox0 + p;
    const unsigned short* rp = ycl + prow * 128;
    float vs[16];
    #pragma unroll
    for (int q = 0; q < 4; ++q) {
        ushort4v rh = *reinterpret_cast<const ushort4v*>(rp + (q + 4) * 16 + 4 * h);
        ushort4v rl = *reinterpret_cast<const ushort4v*>(rp + (q + 4) * 16 + 8 + 4 * h);
        #pragma unroll
        for (int r = 0; r < 4; ++r)
            vs[q * 4 + r] = silu_f(acc[q * 4 + r]) + bf2f(rh[r]) + bf2f(rl[r]);
    }

    __syncthreads();
    {
        const int rec = wv * 32 + p;
        const int pm = rec & 7;
        #pragma unroll
        for (int q = 0; q < 4; ++q) {
            ushort4v hv, lv;
            #pragma unroll
            for (int r = 0; r < 4; ++r) {
                unsigned short hh = bfhi(vs[q * 4 + r]);
                hv[r] = hh; lv[r] = bfhi(vs[q * 4 + r] - bf2f(hh));
            }
            *reinterpret_cast<ushort4v*>(&lds[rec * 64 + (((2 * q)     ^ pm) * 8) + 4 * h]) = hv;
            *reinterpret_cast<ushort4v*>(&lds[rec * 64 + (((2 * q + 1) ^ pm) * 8) + 4 * h]) = lv;
        }
    }
    __syncthreads();

    const int cc = wv & 1;
    #pragma unroll
    for (int g2 = 0; g2 < 2; ++g2) {
        const int rowg = (wv >> 1) + g2 * 4;
        const int oyg = oy0 + rowg;
        const long pg = (long)n * 25600 + (long)oyg * 160 + ox0 + p;

        f32x16 a2;
        #pragma unroll
        for (int q = 0; q < 4; ++q) {
            f32x4 b4 = *reinterpret_cast<const f32x4*>(&bc1[cc * 32 + q * 8 + 4 * h]);
            #pragma unroll
            for (int r = 0; r < 4; ++r) a2[q * 4 + r] = b4[r];
        }

        #pragma unroll
        for (int rnd = 0; rnd < 4; ++rnd) {
            const unsigned short* sp = ycl + pg * 128 + (rnd * 4 + 2 * h) * 8;
            short8 Bh = *reinterpret_cast<const short8*>(sp);
            short8 Bl = *reinterpret_cast<const short8*>(sp + 8);
            const unsigned short* fb = wfrc + (rnd * 2 + cc) * 1024 + lane * 8;
            short8 Awh = *reinterpret_cast<const short8*>(fb);
            short8 Awl = *reinterpret_cast<const short8*>(fb + 512);
            a2 = __builtin_amdgcn_mfma_f32_32x32x16_bf16(Awh, Bh, a2, 0, 0, 0);
            a2 = __builtin_amdgcn_mfma_f32_32x32x16_bf16(Awh, Bl, a2, 0, 0, 0);
            a2 = __builtin_amdgcn_mfma_f32_32x32x16_bf16(Awl, Bh, a2, 0, 0, 0);
        }
        const int recb = rowg * 32 + p;
        const int pmb = recb & 7;
        #pragma unroll
        for (int rnd = 0; rnd < 2; ++rnd) {
            const unsigned short* t = &lds[recb * 64];
            short8 Bh = *reinterpret_cast<const short8*>(t + (((4*rnd + 2*h)     ^ pmb) * 8));
            short8 Bl = *reinterpret_cast<const short8*>(t + (((4*rnd + 2*h + 1) ^ pmb) * 8));
            const unsigned short* fb = wfrc + ((4 + rnd) * 2 + cc) * 1024 + lane * 8;
            short8 Awh = *reinterpret_cast<const short8*>(fb);
            short8 Awl = *reinterpret_cast<const short8*>(fb + 512);
            a2 = __builtin_amdgcn_mfma_f32_32x32x16_bf16(Awh, Bh, a2, 0, 0, 0);
            a2 = __builtin_amdgcn_mfma_f32_32x32x16_bf16(Awh, Bl, a2, 0, 0, 0);
            a2 = __builtin_amdgcn_mfma_f32_32x32x16_bf16(Awl, Bh, a2, 0, 0, 0);
        }

        const int xx = ox0 + p;
        const int pl = (oyg & 1) * 2 + (xx & 1);
        unsigned short* op = h2p + (((long)n * 4 + pl) * 6400 + (oyg >> 1) * 80 + (xx >> 1)) * 128;
        #pragma unroll
        for (int q = 0; q < 4; ++q) {
            ushort4v hv, lv;
            #pragma unroll
            for (int r = 0; r < 4; ++r) {
                float v = silu_f(a2[q * 4 + r]);
                unsigned short hh = bfhi(v);
                hv[r] = hh; lv[r] = bfhi(v - bf2f(hh));
            }
            const int gq = cc * 4 + q;
            *reinterpret_cast<ushort4v*>(op + gq * 16 + 4 * h)     = hv;
            *reinterpret_cast<ushort4v*>(op + gq * 16 + 8 + 4 * h) = lv;
        }
    }
}

// ============ conv3: 64->128 s2 3x3, SINGLE kernel, 4 staging rounds ========
__global__ __launch_bounds__(512, 4) void conv3_one(
    const unsigned short* __restrict__ h2p, const unsigned short* __restrict__ wfr,
    const float* __restrict__ bias, float* __restrict__ outf)
{
    __shared__ unsigned short lds[34848];        // tile 1089 x 32 ush (69.7 KB)
    const int tid = threadIdx.x;
    const int wv = tid >> 6, lane = tid & 63;
    const int p = lane & 31, h = lane >> 5;
    const int bx = blockIdx.x % 5, by = blockIdx.x / 5;
    const int ox0 = bx * 16, oy0 = by * 16;
    const int cg = blockIdx.y;
    const int co0 = cg * 64;
    const int n = blockIdx.z;

    f32x16 acc[2];
    #pragma unroll
    for (int cc = 0; cc < 2; ++cc)
        #pragma unroll
        for (int q = 0; q < 4; ++q) {
            f32x4 b4 = *reinterpret_cast<const f32x4*>(&bias[co0 + cc * 32 + q * 8 + 4 * h]);
            #pragma unroll
            for (int r = 0; r < 4; ++r) acc[cc][q * 4 + r] = b4[r];
        }

    for (int rr = 0; rr < 4; ++rr) {
        __syncthreads();
        for (int u = tid; u < 4356; u += 512) {
            const int rec = u >> 2, s = u & 3;
            int gp, row, col;
            if (rec < 256)      { gp = 0; row = rec >> 4; col = rec & 15; }
            else if (rec < 528) { gp = 1; int r2 = rec - 256; row = r2 / 17; col = r2 - row * 17; }
            else if (rec < 800) { gp = 2; int r2 = rec - 528; row = r2 >> 4; col = r2 & 15; }
            else                { gp = 3; int r2 = rec - 800; row = r2 / 17; col = r2 - row * 17; }
            const int gr = (gp >= 2) ? oy0 - 1 + row : oy0 + row;
            const int gc = (gp & 1)  ? ox0 - 1 + col : ox0 + col;
            uint4v val = {0, 0, 0, 0};
            if (gr >= 0 && gr < 80 && gc >= 0 && gc < 80)
                val = *reinterpret_cast<const uint4v*>(
                    h2p + (((long)n * 4 + gp) * 6400 + gr * 80 + gc) * 128 + (rr * 4 + s) * 8);
            *reinterpret_cast<uint4v*>(&lds[rec * 32 + ((s ^ ((rec >> 1) & 3)) * 8)]) = val;
        }
        __syncthreads();

        #pragma unroll
        for (int tap = 0; tap < 9; ++tap) {
            const int dy = tap / 3 - 1, dx = tap % 3 - 1;
            const int ppy = dy & 1, ppx = dx & 1;
            const int toy = ppy ? ((dy == -1) ? 0 : 1) : 0;
            const int tox = ppx ? ((dx == -1) ? 0 : 1) : 0;
            const int gp = ppy * 2 + ppx;
            const int base = (gp == 0) ? 0 : (gp == 1) ? 256 : (gp == 2) ? 528 : 800;
            const int W = ppx ? 17 : 16;
            const int rl = wv * 2 + (p >> 4), cl = p & 15;
            const int rec = base + (ppy ? (rl + toy) : rl) * W + (cl + tox);
            const unsigned short* t = &lds[rec * 32];
            const int pm = (rec >> 1) & 3;
            short8 Bh = *reinterpret_cast<const short8*>(t + (((2*h)     ^ pm) * 8));
            short8 Bl = *reinterpret_cast<const short8*>(t + (((2*h + 1) ^ pm) * 8));
            #pragma unroll
            for (int cc = 0; cc < 2; ++cc) {
                const unsigned short* fb =
                    wfr + (((cg * 9 + tap) * 4 + rr) * 2 + cc) * 1024 + lane * 8;
                short8 Awh = *reinterpret_cast<const short8*>(fb);
                short8 Awl = *reinterpret_cast<const short8*>(fb + 512);
                acc[cc] = __builtin_amdgcn_mfma_f32_32x32x16_bf16(Awh, Bh, acc[cc], 0, 0, 0);
                acc[cc] = __builtin_amdgcn_mfma_f32_32x32x16_bf16(Awh, Bl, acc[cc], 0, 0, 0);
                acc[cc] = __builtin_amdgcn_mfma_f32_32x32x16_bf16(Awl, Bh, acc[cc], 0, 0, 0);
            }
        }
    }

    const int rl = wv * 2 + (p >> 4);
    const int oy = oy0 + rl;
    const int pxg = oy * 80 + ox0 + (p & 15);
    #pragma unroll
    for (int cc = 0; cc < 2; ++cc)
        #pragma unroll
        for (int q = 0; q < 4; ++q)
            #pragma unroll
            for (int r = 0; r < 4; ++r) {
                const int co = co0 + cc * 32 + q * 8 + 4 * h + r;
                outf[((long)n * 128 + co) * 6400 + pxg] = silu_f(acc[cc][q * 4 + r]);
            }
}

extern "C" void kernel_launch(void* const* d_in, const int* in_sizes, int n_in,
                              void* d_out, int out_size, void* d_ws, size_t ws_size,
                              hipStream_t stream) {
    const float* x   = (const float*)d_in[0];
    const float* w0  = (const float*)d_in[1];
    const float* b0  = (const float*)d_in[2];
    const float* w1  = (const float*)d_in[3];
    const float* b1  = (const float*)d_in[4];
    const float* wc0 = (const float*)d_in[5];
    const float* bc0 = (const float*)d_in[6];
    const float* wb1 = (const float*)d_in[7];
    const float* bb1 = (const float*)d_in[8];
    const float* wb2 = (const float*)d_in[9];
    const float* bb2 = (const float*)d_in[10];
    const float* wc1 = (const float*)d_in[11];
    const float* bc1 = (const float*)d_in[12];
    const float* w3  = (const float*)d_in[13];
    const float* b3  = (const float*)d_in[14];

    unsigned short* u = (unsigned short*)d_ws;
    unsigned short* ycl  = u + 52428800L;
    unsigned short* b1cl = u + 26214400L;
    unsigned short* h2p  = u;
    unsigned short* w3a  = u + 39321600L;    // free slot (old bcl region)

    unsigned short* wsa = (unsigned short*)d_out;
    unsigned short* a_conv1 = wsa;
    unsigned short* a_wc0   = wsa + 36 * 1024;
    unsigned short* a_wb1   = wsa + 44 * 1024;
    unsigned short* a_wb2   = wsa + 62 * 1024;
    unsigned short* a_wc1   = wsa + 80 * 1024;

    prep_small<<<dim3(24, 1, 1), dim3(256, 1, 1), 0, stream>>>(
        w1, wc0, wb1, wb2, wc1, w0, wsa);

    prep_w3<<<dim3(36, 1, 1), dim3(256, 1, 1), 0, stream>>>(w3, w3a);

    // STEM: conv0 + conv1 + wc0 fused -> ycl (32x2 tile, depth-1 prefetch,
    // unclamped interior gathers)
    stem_fused<<<dim3(400, 1, 8), dim3(256, 1, 1), 0, stream>>>(
        x, a_conv1, a_wc0, b0, b1, bc0, ycl);

    wb3x3<<<dim3(100, 1, 8), dim3(512, 1, 1), 0, stream>>>(
        ycl, 128, 8, a_wb1, bb1, b1cl);

    wb2_wc1<<<dim3(100, 1, 8), dim3(512, 1, 1), 0, stream>>>(
        b1cl, ycl, a_wb2, a_wc1, bb2, bc1, h2p);

    conv3_one<<<dim3(25, 2, 8), dim3(512, 1, 1), 0, stream>>>(h2p, w3a, b3, (float*)d_out);
}

// Round 20
// 232.613 us; speedup vs baseline: 1.0637x; 1.0637x over previous
//
#include <hip/hip_runtime.h>
#include <hip/hip_bf16.h>

typedef __attribute__((ext_vector_type(8))) short short8;
typedef __attribute__((ext_vector_type(16))) float f32x16;
typedef __attribute__((ext_vector_type(4))) float f32x4;
typedef __attribute__((ext_vector_type(4))) unsigned int uint4v;
typedef __attribute__((ext_vector_type(4))) unsigned short ushort4v;

__device__ __forceinline__ float silu_f(float v) {
    return v * __builtin_amdgcn_rcpf(1.0f + __expf(-v));
}
__device__ __forceinline__ unsigned short bfhi(float v) {
    __hip_bfloat16 h = __float2bfloat16(v);
    return *reinterpret_cast<unsigned short*>(&h);
}
__device__ __forceinline__ float bf2f(unsigned short u) {
    __hip_bfloat16 h;
    *reinterpret_cast<unsigned short*>(&h) = u;
    return __bfloat162float(h);
}

// ======= weight prep: f32 -> bf16 hi/lo fragments (pf*1024 + lane*8, lo +512)
// arena (in d_out): conv1 @0 (36pf), wc0 @36 (8pf), wb1 @44 (18pf),
//   wb2 @62 (18pf), wc1 @80 (12pf), w0 @92 (2pf; K=32 padded from 27). 94 pf.
__global__ __launch_bounds__(256) void prep_small(
    const float* __restrict__ w1, const float* __restrict__ wc0,
    const float* __restrict__ wb1, const float* __restrict__ wb2,
    const float* __restrict__ wc1, const float* __restrict__ w0,
    unsigned short* __restrict__ arena)
{
    const int u = blockIdx.x * 256 + threadIdx.x;   // 0..6015
    if (u >= 6016) return;
    const int lane = u & 63, pf = u >> 6;
    float wv[8];
    if (pf < 36) {
        const int q = pf, cc = q & 1, rnd = (q >> 1) & 1, tap = q >> 2;
        const int co = cc * 32 + (lane & 31), ci0 = rnd * 16 + (lane >> 5) * 8;
        #pragma unroll
        for (int j = 0; j < 8; ++j) wv[j] = w1[(co * 32 + ci0 + j) * 9 + tap];
    } else if (pf < 44) {
        const int q = pf - 36, cc = q & 1, rnd = q >> 1;
        const int co = cc * 32 + (lane & 31), ci0 = rnd * 16 + (lane >> 5) * 8;
        #pragma unroll
        for (int j = 0; j < 8; ++j) wv[j] = wc0[co * 64 + ci0 + j];
    } else if (pf < 62) {
        const int q = pf - 44, rnd = q & 1, tap = q >> 1;
        const int co = lane & 31, ci0 = rnd * 16 + (lane >> 5) * 8;
        #pragma unroll
        for (int j = 0; j < 8; ++j) wv[j] = wb1[(co * 32 + ci0 + j) * 9 + tap];
    } else if (pf < 80) {
        const int q = pf - 62, rnd = q & 1, tap = q >> 1;
        const int co = lane & 31, ci0 = rnd * 16 + (lane >> 5) * 8;
        #pragma unroll
        for (int j = 0; j < 8; ++j) wv[j] = wb2[(co * 32 + ci0 + j) * 9 + tap];
    } else if (pf < 92) {
        const int q = pf - 80, cc = q & 1, rnd = q >> 1;
        const int co = cc * 32 + (lane & 31), ci0 = rnd * 16 + (lane >> 5) * 8;
        #pragma unroll
        for (int j = 0; j < 8; ++j) wv[j] = wc1[co * 96 + ci0 + j];
    } else {
        const int co = lane & 31;
        const int k0 = (pf - 92) * 16 + (lane >> 5) * 8;
        #pragma unroll
        for (int j = 0; j < 8; ++j) {
            const int k = k0 + j;
            wv[j] = (k < 27) ? w0[(co * 3 + k / 9) * 9 + (k % 9)] : 0.0f;
        }
    }
    unsigned short hs[8], ls[8];
    #pragma unroll
    for (int j = 0; j < 8; ++j) {
        unsigned short hh = bfhi(wv[j]);
        hs[j] = hh; ls[j] = bfhi(wv[j] - bf2f(hh));
    }
    *reinterpret_cast<short8*>(&arena[pf * 1024 + lane * 8])       = *(short8*)hs;
    *reinterpret_cast<short8*>(&arena[pf * 1024 + 512 + lane * 8]) = *(short8*)ls;
}

// arena2 (in ws): w3, pf = ((cg*9+tap)*4 + rr)*2+cc, rr = ci/16. 144 pf
__global__ __launch_bounds__(256) void prep_w3(
    const float* __restrict__ w3, unsigned short* __restrict__ arena)
{
    const int u = blockIdx.x * 256 + threadIdx.x;   // 0..9215
    const int lane = u & 63, pf = u >> 6;
    const int cc = pf & 1, rr = (pf >> 1) & 3, t9 = pf >> 3;
    const int tap = t9 % 9, cg = t9 / 9;
    const int co = cg * 64 + cc * 32 + (lane & 31);
    const int ci0 = rr * 16 + (lane >> 5) * 8;
    unsigned short hs[8], ls[8];
    #pragma unroll
    for (int j = 0; j < 8; ++j) {
        float wv = w3[(co * 64 + ci0 + j) * 9 + tap];
        unsigned short hh = bfhi(wv);
        hs[j] = hh; ls[j] = bfhi(wv - bf2f(hh));
    }
    *reinterpret_cast<short8*>(&arena[pf * 1024 + lane * 8])       = *(short8*)hs;
    *reinterpret_cast<short8*>(&arena[pf * 1024 + 512 + lane * 8]) = *(short8*)ls;
}

// ---- stem phase-A helpers (325-rec 32x2 geometry, round-12/15 proven) -----
struct GDesc {
    int rc, Bsafe, Y, X;
    bool validR, valid, fastw;
};

__device__ __forceinline__ GDesc stem_desc(int g, int p, int ox0, int oy0) {
    GDesc d;
    d.rc = g * 32 + p;
    d.validR = d.rc < 325;
    const int rec_c = d.validR ? d.rc : 324;
    int gp, row, col;
    if (rec_c < 64)       { gp = 0; row = rec_c >> 5; col = rec_c & 31; }
    else if (rec_c < 130) { gp = 1; int r2 = rec_c - 64;  row = r2 / 33; col = r2 - row * 33; }
    else if (rec_c < 226) { gp = 2; int r2 = rec_c - 130; row = r2 >> 5; col = r2 & 31; }
    else                  { gp = 3; int r2 = rec_c - 226; row = r2 / 33; col = r2 - row * 33; }
    const int gr = (gp >= 2) ? oy0 - 1 + row : oy0 + row;
    const int gc = (gp & 1)  ? ox0 - 1 + col : ox0 + col;
    d.valid = d.validR && ((unsigned)gr < 160u) && ((unsigned)gc < 160u);
    d.Y = 2 * gr + (gp >> 1);
    d.X = 2 * gc + (gp & 1);
    d.Bsafe = d.valid ? (1280 * d.Y + 2 * d.X) : 641;
    const bool interior = d.valid && gr > 0 && gr < 159 && gc > 0 && gc < 159;
    d.fastw = __all(interior);
    return d;
}

__device__ __forceinline__ void stem_issue(
    int Bsafe, const int* doff, const float* __restrict__ xb, float* xv)
{
    #pragma unroll
    for (int idx = 0; idx < 16; ++idx) {
        int a = Bsafe + doff[idx];
        a = max(a, 0);
        a = min(a, 1228799);
        xv[idx] = xb[a];
    }
}

__device__ __forceinline__ void stem_process(
    const GDesc& d, const float* xv, unsigned short* lds,
    const unsigned short* __restrict__ wfr, const float* __restrict__ b0,
    int h, int h8, int lane)
{
    f32x16 a0;
    #pragma unroll
    for (int q = 0; q < 4; ++q) {
        f32x4 b4 = *reinterpret_cast<const f32x4*>(&b0[q * 8 + 4 * h]);
        #pragma unroll
        for (int r2 = 0; r2 < 4; ++r2) a0[q * 4 + r2] = b4[r2];
    }

    #pragma unroll
    for (int rnd = 0; rnd < 2; ++rnd) {
        unsigned short hs[8], ls[8];
        if (d.fastw) {
            #pragma unroll
            for (int j = 0; j < 8; ++j) {
                float v = xv[rnd * 8 + j];
                if (rnd == 1 && j >= 3) v = (h == 0) ? v : 0.0f;
                unsigned short hh = bfhi(v);
                hs[j] = hh; ls[j] = bfhi(v - bf2f(hh));
            }
        } else {
            #pragma unroll
            for (int j = 0; j < 8; ++j) {
                const int k = rnd * 16 + h8 + j;
                const int ci = (k * 57) >> 9;
                const int tap = k - 9 * ci;
                const int dy = (tap * 11) >> 5, dx = tap - 3 * dy;
                const int iy = 2 * d.Y + dy - 1;
                const int ix = 2 * d.X + dx - 1;
                bool ok = d.valid && ((unsigned)iy < 640u) && ((unsigned)ix < 640u);
                if (rnd == 1 && j >= 3) ok = ok && (h == 0);
                float v = ok ? xv[rnd * 8 + j] : 0.0f;
                unsigned short hh = bfhi(v);
                hs[j] = hh; ls[j] = bfhi(v - bf2f(hh));
            }
        }
        short8 Bh = *(short8*)hs, Bl = *(short8*)ls;
        const unsigned short* fb = wfr + (92 + rnd) * 1024 + lane * 8;
        short8 Awh = *reinterpret_cast<const short8*>(fb);
        short8 Awl = *reinterpret_cast<const short8*>(fb + 512);
        a0 = __builtin_amdgcn_mfma_f32_32x32x16_bf16(Awh, Bh, a0, 0, 0, 0);
        a0 = __builtin_amdgcn_mfma_f32_32x32x16_bf16(Awh, Bl, a0, 0, 0, 0);
        a0 = __builtin_amdgcn_mfma_f32_32x32x16_bf16(Awl, Bh, a0, 0, 0, 0);
    }

    if (d.validR) {
        const int pm = d.rc & 7;
        #pragma unroll
        for (int q = 0; q < 4; ++q) {
            ushort4v hv, lv;
            #pragma unroll
            for (int r2 = 0; r2 < 4; ++r2) {
                float v = d.valid ? silu_f(a0[q * 4 + r2]) : 0.0f;
                unsigned short hh = bfhi(v);
                hv[r2] = hh; lv[r2] = bfhi(v - bf2f(hh));
            }
            *reinterpret_cast<ushort4v*>(&lds[d.rc * 64 + (((2 * q)     ^ pm) * 8) + 4 * h]) = hv;
            *reinterpret_cast<ushort4v*>(&lds[d.rc * 64 + (((2 * q + 1) ^ pm) * 8) + 4 * h]) = lv;
        }
    }
}

// ============ STEM: conv0 (3->32 s2) + conv1 (32->64 s2 3x3) + wc0 (1x1) ====
// Round-12 geometry (256 thr, 32x2 tile); phase A with depth-1 prefetch.
__global__ __launch_bounds__(256, 4) void stem_fused(
    const float* __restrict__ x, const unsigned short* __restrict__ wfr,
    const unsigned short* __restrict__ wc0fr, const float* __restrict__ b0,
    const float* __restrict__ bias, const float* __restrict__ bc0,
    unsigned short* __restrict__ ycl)
{
    __shared__ unsigned short lds[20800];        // 325 recs x 64 ush = 41.6 KB
    const int tid = threadIdx.x;
    const int wv = tid >> 6, lane = tid & 63;
    const int p = lane & 31, h = lane >> 5;
    const int r = wv >> 1, cc = wv & 1;
    const int bx = blockIdx.x % 5, by = blockIdx.x / 5;
    const int ox0 = bx * 32, oy0 = by * 2;
    const int n = blockIdx.z;
    const float* xb = x + (long)n * 1228800;

    const int h8 = h * 8;
    int doff[16];
    #pragma unroll
    for (int idx = 0; idx < 16; ++idx) {
        const int k = (idx >> 3) * 16 + h8 + (idx & 7);
        if (k < 27) {
            const int ci = (k * 57) >> 9;
            const int tap = k - 9 * ci;
            const int dy = (tap * 11) >> 5, dx = tap - 3 * dy;
            doff[idx] = ci * 409600 + (dy - 1) * 640 + (dx - 1);
        } else {
            doff[idx] = 0;
        }
    }

    // ---- phase A with depth-1 prefetch: groups wv, wv+4, (wv+8 if wv<3)
    {
        GDesc d0 = stem_desc(wv, p, ox0, oy0);
        float xva[16];
        stem_issue(d0.Bsafe, doff, xb, xva);

        GDesc d1 = stem_desc(wv + 4, p, ox0, oy0);
        float xvb[16];
        stem_issue(d1.Bsafe, doff, xb, xvb);

        stem_process(d0, xva, lds, wfr, b0, h, h8, lane);

        if (wv < 3) {
            GDesc d2 = stem_desc(wv + 8, p, ox0, oy0);
            stem_issue(d2.Bsafe, doff, xb, xva);
            stem_process(d1, xvb, lds, wfr, b0, h, h8, lane);
            stem_process(d2, xva, lds, wfr, b0, h, h8, lane);
        } else {
            stem_process(d1, xvb, lds, wfr, b0, h, h8, lane);
        }
    }
    __syncthreads();

    // ---- conv1 K-loop from LDS h0 tile (no staging, no barriers)
    f32x16 acc;
    #pragma unroll
    for (int q = 0; q < 4; ++q) {
        f32x4 b4 = *reinterpret_cast<const f32x4*>(&bias[cc * 32 + q * 8 + 4 * h]);
        #pragma unroll
        for (int r2 = 0; r2 < 4; ++r2) acc[q * 4 + r2] = b4[r2];
    }
    #pragma unroll
    for (int c = 0; c < 2; ++c) {
        #pragma unroll
        for (int tap = 0; tap < 9; ++tap) {
            const int dy = tap / 3 - 1, dx = tap % 3 - 1;
            const int ppy = dy & 1, ppx = dx & 1;
            const int toy = ppy ? ((dy == -1) ? 0 : 1) : 0;
            const int tox = ppx ? ((dx == -1) ? 0 : 1) : 0;
            const int gp = ppy * 2 + ppx;
            const int base = (gp == 0) ? 0 : (gp == 1) ? 64 : (gp == 2) ? 130 : 226;
            const int W = ppx ? 33 : 32;
            const int rec = base + (ppy ? (r + toy) : r) * W + (p + tox);
            const unsigned short* t = &lds[rec * 64];
            const int pm = rec & 7;
            short8 Bh = *reinterpret_cast<const short8*>(t + (((4 * c + 2 * h)     ^ pm) * 8));
            short8 Bl = *reinterpret_cast<const short8*>(t + (((4 * c + 2 * h + 1) ^ pm) * 8));
            const unsigned short* fb = wfr + ((tap * 2 + c) * 2 + cc) * 1024 + lane * 8;
            short8 Awh = *reinterpret_cast<const short8*>(fb);
            short8 Awl = *reinterpret_cast<const short8*>(fb + 512);
            acc = __builtin_amdgcn_mfma_f32_32x32x16_bf16(Awh, Bh, acc, 0, 0, 0);
            acc = __builtin_amdgcn_mfma_f32_32x32x16_bf16(Awh, Bl, acc, 0, 0, 0);
            acc = __builtin_amdgcn_mfma_f32_32x32x16_bf16(Awl, Bh, acc, 0, 0, 0);
        }
    }

    // ---- stage y = silu(conv1) to LDS (64 recs x 128 ush), aliases h0 tile
    __syncthreads();
    {
        const int rec2 = r * 32 + p;
        #pragma unroll
        for (int q = 0; q < 4; ++q) {
            ushort4v hv, lv;
            #pragma unroll
            for (int r2 = 0; r2 < 4; ++r2) {
                float v = silu_f(acc[q * 4 + r2]);
                unsigned short hh = bfhi(v);
                hv[r2] = hh; lv[r2] = bfhi(v - bf2f(hh));
            }
            const int lsh = (2 * (cc * 4 + q))     ^ (rec2 & 15);
            const int lsl = (2 * (cc * 4 + q) + 1) ^ (rec2 & 15);
            *reinterpret_cast<ushort4v*>(&lds[rec2 * 128 + lsh * 8 + 4 * h]) = hv;
            *reinterpret_cast<ushort4v*>(&lds[rec2 * 128 + lsl * 8 + 4 * h]) = lv;
        }
    }
    __syncthreads();

    // ---- wc0: 1x1 64->64 from LDS y-tile; wave owns cc output chunk
    f32x16 a2;
    #pragma unroll
    for (int q = 0; q < 4; ++q) {
        f32x4 b4 = *reinterpret_cast<const f32x4*>(&bc0[cc * 32 + q * 8 + 4 * h]);
        #pragma unroll
        for (int r2 = 0; r2 < 4; ++r2) a2[q * 4 + r2] = b4[r2];
    }
    {
        const int rec2 = r * 32 + p;
        #pragma unroll
        for (int rnd = 0; rnd < 4; ++rnd) {
            const int sh = (4 * rnd + 2 * h)     ^ (rec2 & 15);
            const int sl = (4 * rnd + 2 * h + 1) ^ (rec2 & 15);
            short8 Bh = *reinterpret_cast<const short8*>(&lds[rec2 * 128 + sh * 8]);
            short8 Bl = *reinterpret_cast<const short8*>(&lds[rec2 * 128 + sl * 8]);
            const unsigned short* fb = wc0fr + (rnd * 2 + cc) * 1024 + lane * 8;
            short8 Awh = *reinterpret_cast<const short8*>(fb);
            short8 Awl = *reinterpret_cast<const short8*>(fb + 512);
            a2 = __builtin_amdgcn_mfma_f32_32x32x16_bf16(Awh, Bh, a2, 0, 0, 0);
            a2 = __builtin_amdgcn_mfma_f32_32x32x16_bf16(Awh, Bl, a2, 0, 0, 0);
            a2 = __builtin_amdgcn_mfma_f32_32x32x16_bf16(Awl, Bh, a2, 0, 0, 0);
        }
    }

    const int oy = oy0 + r;
    unsigned short* op = ycl + ((long)n * 25600 + (long)oy * 160 + ox0 + p) * 128;
    #pragma unroll
    for (int q = 0; q < 4; ++q) {
        ushort4v hv, lv;
        #pragma unroll
        for (int r2 = 0; r2 < 4; ++r2) {
            float v = silu_f(a2[q * 4 + r2]);
            unsigned short hh = bfhi(v);
            hv[r2] = hh; lv[r2] = bfhi(v - bf2f(hh));
        }
        const int gq = cc * 4 + q;
        *reinterpret_cast<ushort4v*>(op + gq * 16 + 4 * h)     = hv;
        *reinterpret_cast<ushort4v*>(op + gq * 16 + 8 + 4 * h) = lv;
    }
}

// ============ wb1: 32->32 s1 3x3, tile-only LDS, frags from global ==========
__global__ __launch_bounds__(512, 4) void wb3x3(
    const unsigned short* __restrict__ in, int inRec, int inSlot0,
    const unsigned short* __restrict__ wfr, const float* __restrict__ bias,
    unsigned short* __restrict__ outb)
{
    __shared__ unsigned short lds[21760];        // tile 34x10 x 64 ush (43.5 KB)
    const int tid = threadIdx.x;
    const int wv = tid >> 6, lane = tid & 63;
    const int p = lane & 31, h = lane >> 5;
    const int bx = blockIdx.x % 5, by = blockIdx.x / 5;
    const int ox0 = bx * 32, oy0 = by * 8;
    const int n = blockIdx.z;

    for (int u = tid; u < 2720; u += 512) {      // tile 34x10, 8 slots/rec
        const int rec = u >> 3, s = u & 7;
        const int row = rec / 34, col = rec - row * 34;
        const int gr = oy0 - 1 + row, gc = ox0 - 1 + col;
        uint4v val = {0, 0, 0, 0};
        if (gr >= 0 && gr < 160 && gc >= 0 && gc < 160)
            val = *reinterpret_cast<const uint4v*>(
                in + ((long)n * 25600 + gr * 160 + gc) * inRec + (inSlot0 + s) * 8);
        *reinterpret_cast<uint4v*>(&lds[rec * 64 + ((s ^ (rec & 7)) * 8)]) = val;
    }

    f32x16 acc;
    #pragma unroll
    for (int q = 0; q < 4; ++q) {
        f32x4 b4 = *reinterpret_cast<const f32x4*>(&bias[q * 8 + 4 * h]);
        #pragma unroll
        for (int r = 0; r < 4; ++r) acc[q * 4 + r] = b4[r];
    }
    __syncthreads();

    #pragma unroll
    for (int tap = 0; tap < 9; ++tap) {
        const int dy = tap / 3 - 1, dx = tap % 3 - 1;
        const int rec = (wv + dy + 1) * 34 + (p + dx + 1);
        const unsigned short* t = &lds[rec * 64];
        short8 Bh[2], Bl[2];
        #pragma unroll
        for (int rnd = 0; rnd < 2; ++rnd) {
            Bh[rnd] = *reinterpret_cast<const short8*>(t + (((rnd*4 + 2*h)     ^ (rec & 7)) * 8));
            Bl[rnd] = *reinterpret_cast<const short8*>(t + (((rnd*4 + 2*h + 1) ^ (rec & 7)) * 8));
        }
        #pragma unroll
        for (int rnd = 0; rnd < 2; ++rnd) {
            const unsigned short* fb = wfr + (tap * 2 + rnd) * 1024 + lane * 8;
            short8 Awh = *reinterpret_cast<const short8*>(fb);
            short8 Awl = *reinterpret_cast<const short8*>(fb + 512);
            acc = __builtin_amdgcn_mfma_f32_32x32x16_bf16(Awh, Bh[rnd], acc, 0, 0, 0);
            acc = __builtin_amdgcn_mfma_f32_32x32x16_bf16(Awh, Bl[rnd], acc, 0, 0, 0);
            acc = __builtin_amdgcn_mfma_f32_32x32x16_bf16(Awl, Bh[rnd], acc, 0, 0, 0);
        }
    }

    const int oy = oy0 + wv;
    const long prow = (long)n * 25600 + (long)oy * 160 + ox0 + p;
    unsigned short* op = outb + prow * 64;
    #pragma unroll
    for (int q = 0; q < 4; ++q) {
        ushort4v hv, lv;
        #pragma unroll
        for (int r = 0; r < 4; ++r) {
            float v = silu_f(acc[q * 4 + r]);
            unsigned short hh = bfhi(v);
            hv[r] = hh; lv[r] = bfhi(v - bf2f(hh));
        }
        *reinterpret_cast<ushort4v*>(op + q * 16 + 4 * h)     = hv;
        *reinterpret_cast<ushort4v*>(op + q * 16 + 8 + 4 * h) = lv;
    }
}

// ============ wb2+wc1 FUSED: 3x3 32->32 (+resid) then 1x1 96->64 ============
// wb2's b-tile (32x8 px) goes to LDS (no bcl round-trip); wc1 reads ycl from
// global (4 rnds) + b from LDS (2 rnds); writes h2p parity-split.
__global__ __launch_bounds__(512, 4) void wb2_wc1(
    const unsigned short* __restrict__ b1cl, const unsigned short* __restrict__ ycl,
    const unsigned short* __restrict__ wfr2, const unsigned short* __restrict__ wfrc,
    const float* __restrict__ bb2, const float* __restrict__ bc1,
    unsigned short* __restrict__ h2p)
{
    __shared__ unsigned short lds[21760];        // 34x10 tile / 256x64 b-tile
    const int tid = threadIdx.x;
    const int wv = tid >> 6, lane = tid & 63;
    const int p = lane & 31, h = lane >> 5;
    const int bx = blockIdx.x % 5, by = blockIdx.x / 5;
    const int ox0 = bx * 32, oy0 = by * 8;
    const int n = blockIdx.z;

    // ---- stage b1cl tile 34x10 (8 slots/rec)
    for (int u = tid; u < 2720; u += 512) {
        const int rec = u >> 3, s = u & 7;
        const int row = rec / 34, col = rec - row * 34;
        const int gr = oy0 - 1 + row, gc = ox0 - 1 + col;
        uint4v val = {0, 0, 0, 0};
        if (gr >= 0 && gr < 160 && gc >= 0 && gc < 160)
            val = *reinterpret_cast<const uint4v*>(
                b1cl + ((long)n * 25600 + gr * 160 + gc) * 64 + s * 8);
        *reinterpret_cast<uint4v*>(&lds[rec * 64 + ((s ^ (rec & 7)) * 8)]) = val;
    }

    f32x16 acc;
    #pragma unroll
    for (int q = 0; q < 4; ++q) {
        f32x4 b4 = *reinterpret_cast<const f32x4*>(&bb2[q * 8 + 4 * h]);
        #pragma unroll
        for (int r = 0; r < 4; ++r) acc[q * 4 + r] = b4[r];
    }
    __syncthreads();

    // ---- wb2 K-loop (9 taps x 2 rnds)
    #pragma unroll
    for (int tap = 0; tap < 9; ++tap) {
        const int dy = tap / 3 - 1, dx = tap % 3 - 1;
        const int rec = (wv + dy + 1) * 34 + (p + dx + 1);
        const unsigned short* t = &lds[rec * 64];
        short8 Bh[2], Bl[2];
        #pragma unroll
        for (int rnd = 0; rnd < 2; ++rnd) {
            Bh[rnd] = *reinterpret_cast<const short8*>(t + (((rnd*4 + 2*h)     ^ (rec & 7)) * 8));
            Bl[rnd] = *reinterpret_cast<const short8*>(t + (((rnd*4 + 2*h + 1) ^ (rec & 7)) * 8));
        }
        #pragma unroll
        for (int rnd = 0; rnd < 2; ++rnd) {
            const unsigned short* fb = wfr2 + (tap * 2 + rnd) * 1024 + lane * 8;
            short8 Awh = *reinterpret_cast<const short8*>(fb);
            short8 Awl = *reinterpret_cast<const short8*>(fb + 512);
            acc = __builtin_amdgcn_mfma_f32_32x32x16_bf16(Awh, Bh[rnd], acc, 0, 0, 0);
            acc = __builtin_amdgcn_mfma_f32_32x32x16_bf16(Awh, Bl[rnd], acc, 0, 0, 0);
            acc = __builtin_amdgcn_mfma_f32_32x32x16_bf16(Awl, Bh[rnd], acc, 0, 0, 0);
        }
    }

    // ---- b = silu(wb2) + x2(ycl ch32-63); compute in regs
    const int oy = oy0 + wv;
    const long prow = (long)n * 25600 + (long)oy * 160 + ox0 + p;
    const unsigned short* rp = ycl + prow * 128;
    float vs[16];
    #pragma unroll
    for (int q = 0; q < 4; ++q) {
        ushort4v rh = *reinterpret_cast<const ushort4v*>(rp + (q + 4) * 16 + 4 * h);
        ushort4v rl = *reinterpret_cast<const ushort4v*>(rp + (q + 4) * 16 + 8 + 4 * h);
        #pragma unroll
        for (int r = 0; r < 4; ++r)
            vs[q * 4 + r] = silu_f(acc[q * 4 + r]) + bf2f(rh[r]) + bf2f(rl[r]);
    }

    // ---- write b-tile to LDS (256 recs x 64 ush), aliases input tile
    __syncthreads();
    {
        const int rec = wv * 32 + p;
        const int pm = rec & 7;
        #pragma unroll
        for (int q = 0; q < 4; ++q) {
            ushort4v hv, lv;
            #pragma unroll
            for (int r = 0; r < 4; ++r) {
                unsigned short hh = bfhi(vs[q * 4 + r]);
                hv[r] = hh; lv[r] = bfhi(vs[q * 4 + r] - bf2f(hh));
            }
            *reinterpret_cast<ushort4v*>(&lds[rec * 64 + (((2 * q)     ^ pm) * 8) + 4 * h]) = hv;
            *reinterpret_cast<ushort4v*>(&lds[rec * 64 + (((2 * q + 1) ^ pm) * 8) + 4 * h]) = lv;
        }
    }
    __syncthreads();

    // ---- wc1 phase: wave = (row-group wv>>1, cc=wv&1); 2 row-groups per wave
    const int cc = wv & 1;
    #pragma unroll
    for (int g2 = 0; g2 < 2; ++g2) {
        const int rowg = (wv >> 1) + g2 * 4;
        const int oyg = oy0 + rowg;
        const long pg = (long)n * 25600 + (long)oyg * 160 + ox0 + p;

        f32x16 a2;
        #pragma unroll
        for (int q = 0; q < 4; ++q) {
            f32x4 b4 = *reinterpret_cast<const f32x4*>(&bc1[cc * 32 + q * 8 + 4 * h]);
            #pragma unroll
            for (int r = 0; r < 4; ++r) a2[q * 4 + r] = b4[r];
        }

        // 4 rnds from ycl (ch 0-63)
        #pragma unroll
        for (int rnd = 0; rnd < 4; ++rnd) {
            const unsigned short* sp = ycl + pg * 128 + (rnd * 4 + 2 * h) * 8;
            short8 Bh = *reinterpret_cast<const short8*>(sp);
            short8 Bl = *reinterpret_cast<const short8*>(sp + 8);
            const unsigned short* fb = wfrc + (rnd * 2 + cc) * 1024 + lane * 8;
            short8 Awh = *reinterpret_cast<const short8*>(fb);
            short8 Awl = *reinterpret_cast<const short8*>(fb + 512);
            a2 = __builtin_amdgcn_mfma_f32_32x32x16_bf16(Awh, Bh, a2, 0, 0, 0);
            a2 = __builtin_amdgcn_mfma_f32_32x32x16_bf16(Awh, Bl, a2, 0, 0, 0);
            a2 = __builtin_amdgcn_mfma_f32_32x32x16_bf16(Awl, Bh, a2, 0, 0, 0);
        }
        // 2 rnds from LDS b-tile (ch 64-95)
        const int recb = rowg * 32 + p;
        const int pmb = recb & 7;
        #pragma unroll
        for (int rnd = 0; rnd < 2; ++rnd) {
            const unsigned short* t = &lds[recb * 64];
            short8 Bh = *reinterpret_cast<const short8*>(t + (((4*rnd + 2*h)     ^ pmb) * 8));
            short8 Bl = *reinterpret_cast<const short8*>(t + (((4*rnd + 2*h + 1) ^ pmb) * 8));
            const unsigned short* fb = wfrc + ((4 + rnd) * 2 + cc) * 1024 + lane * 8;
            short8 Awh = *reinterpret_cast<const short8*>(fb);
            short8 Awl = *reinterpret_cast<const short8*>(fb + 512);
            a2 = __builtin_amdgcn_mfma_f32_32x32x16_bf16(Awh, Bh, a2, 0, 0, 0);
            a2 = __builtin_amdgcn_mfma_f32_32x32x16_bf16(Awh, Bl, a2, 0, 0, 0);
            a2 = __builtin_amdgcn_mfma_f32_32x32x16_bf16(Awl, Bh, a2, 0, 0, 0);
        }

        // write h2p parity-split
        const int xx = ox0 + p;
        const int pl = (oyg & 1) * 2 + (xx & 1);
        unsigned short* op = h2p + (((long)n * 4 + pl) * 6400 + (oyg >> 1) * 80 + (xx >> 1)) * 128;
        #pragma unroll
        for (int q = 0; q < 4; ++q) {
            ushort4v hv, lv;
            #pragma unroll
            for (int r = 0; r < 4; ++r) {
                float v = silu_f(a2[q * 4 + r]);
                unsigned short hh = bfhi(v);
                hv[r] = hh; lv[r] = bfhi(v - bf2f(hh));
            }
            const int gq = cc * 4 + q;
            *reinterpret_cast<ushort4v*>(op + gq * 16 + 4 * h)     = hv;
            *reinterpret_cast<ushort4v*>(op + gq * 16 + 8 + 4 * h) = lv;
        }
    }
}

// ============ conv3: 64->128 s2 3x3, SINGLE kernel, 4 staging rounds ========
__global__ __launch_bounds__(512, 4) void conv3_one(
    const unsigned short* __restrict__ h2p, const unsigned short* __restrict__ wfr,
    const float* __restrict__ bias, float* __restrict__ outf)
{
    __shared__ unsigned short lds[34848];        // tile 1089 x 32 ush (69.7 KB)
    const int tid = threadIdx.x;
    const int wv = tid >> 6, lane = tid & 63;
    const int p = lane & 31, h = lane >> 5;
    const int bx = blockIdx.x % 5, by = blockIdx.x / 5;
    const int ox0 = bx * 16, oy0 = by * 16;
    const int cg = blockIdx.y;
    const int co0 = cg * 64;
    const int n = blockIdx.z;

    f32x16 acc[2];
    #pragma unroll
    for (int cc = 0; cc < 2; ++cc)
        #pragma unroll
        for (int q = 0; q < 4; ++q) {
            f32x4 b4 = *reinterpret_cast<const f32x4*>(&bias[co0 + cc * 32 + q * 8 + 4 * h]);
            #pragma unroll
            for (int r = 0; r < 4; ++r) acc[cc][q * 4 + r] = b4[r];
        }

    for (int rr = 0; rr < 4; ++rr) {
        __syncthreads();
        for (int u = tid; u < 4356; u += 512) {
            const int rec = u >> 2, s = u & 3;
            int gp, row, col;
            if (rec < 256)      { gp = 0; row = rec >> 4; col = rec & 15; }
            else if (rec < 528) { gp = 1; int r2 = rec - 256; row = r2 / 17; col = r2 - row * 17; }
            else if (rec < 800) { gp = 2; int r2 = rec - 528; row = r2 >> 4; col = r2 & 15; }
            else                { gp = 3; int r2 = rec - 800; row = r2 / 17; col = r2 - row * 17; }
            const int gr = (gp >= 2) ? oy0 - 1 + row : oy0 + row;
            const int gc = (gp & 1)  ? ox0 - 1 + col : ox0 + col;
            uint4v val = {0, 0, 0, 0};
            if (gr >= 0 && gr < 80 && gc >= 0 && gc < 80)
                val = *reinterpret_cast<const uint4v*>(
                    h2p + (((long)n * 4 + gp) * 6400 + gr * 80 + gc) * 128 + (rr * 4 + s) * 8);
            *reinterpret_cast<uint4v*>(&lds[rec * 32 + ((s ^ ((rec >> 1) & 3)) * 8)]) = val;
        }
        __syncthreads();

        #pragma unroll
        for (int tap = 0; tap < 9; ++tap) {
            const int dy = tap / 3 - 1, dx = tap % 3 - 1;
            const int ppy = dy & 1, ppx = dx & 1;
            const int toy = ppy ? ((dy == -1) ? 0 : 1) : 0;
            const int tox = ppx ? ((dx == -1) ? 0 : 1) : 0;
            const int gp = ppy * 2 + ppx;
            const int base = (gp == 0) ? 0 : (gp == 1) ? 256 : (gp == 2) ? 528 : 800;
            const int W = ppx ? 17 : 16;
            const int rl = wv * 2 + (p >> 4), cl = p & 15;
            const int rec = base + (ppy ? (rl + toy) : rl) * W + (cl + tox);
            const unsigned short* t = &lds[rec * 32];
            const int pm = (rec >> 1) & 3;
            short8 Bh = *reinterpret_cast<const short8*>(t + (((2*h)     ^ pm) * 8));
            short8 Bl = *reinterpret_cast<const short8*>(t + (((2*h + 1) ^ pm) * 8));
            #pragma unroll
            for (int cc = 0; cc < 2; ++cc) {
                const unsigned short* fb =
                    wfr + (((cg * 9 + tap) * 4 + rr) * 2 + cc) * 1024 + lane * 8;
                short8 Awh = *reinterpret_cast<const short8*>(fb);
                short8 Awl = *reinterpret_cast<const short8*>(fb + 512);
                acc[cc] = __builtin_amdgcn_mfma_f32_32x32x16_bf16(Awh, Bh, acc[cc], 0, 0, 0);
                acc[cc] = __builtin_amdgcn_mfma_f32_32x32x16_bf16(Awh, Bl, acc[cc], 0, 0, 0);
                acc[cc] = __builtin_amdgcn_mfma_f32_32x32x16_bf16(Awl, Bh, acc[cc], 0, 0, 0);
            }
        }
    }

    const int rl = wv * 2 + (p >> 4);
    const int oy = oy0 + rl;
    const int pxg = oy * 80 + ox0 + (p & 15);
    #pragma unroll
    for (int cc = 0; cc < 2; ++cc)
        #pragma unroll
        for (int q = 0; q < 4; ++q)
            #pragma unroll
            for (int r = 0; r < 4; ++r) {
                const int co = co0 + cc * 32 + q * 8 + 4 * h + r;
                outf[((long)n * 128 + co) * 6400 + pxg] = silu_f(acc[cc][q * 4 + r]);
            }
}

extern "C" void kernel_launch(void* const* d_in, const int* in_sizes, int n_in,
                              void* d_out, int out_size, void* d_ws, size_t ws_size,
                              hipStream_t stream) {
    const float* x   = (const float*)d_in[0];
    const float* w0  = (const float*)d_in[1];
    const float* b0  = (const float*)d_in[2];
    const float* w1  = (const float*)d_in[3];
    const float* b1  = (const float*)d_in[4];
    const float* wc0 = (const float*)d_in[5];
    const float* bc0 = (const float*)d_in[6];
    const float* wb1 = (const float*)d_in[7];
    const float* bb1 = (const float*)d_in[8];
    const float* wb2 = (const float*)d_in[9];
    const float* bb2 = (const float*)d_in[10];
    const float* wc1 = (const float*)d_in[11];
    const float* bc1 = (const float*)d_in[12];
    const float* w3  = (const float*)d_in[13];
    const float* b3  = (const float*)d_in[14];

    unsigned short* u = (unsigned short*)d_ws;
    // ws (ushort offsets), peak 157,286,400 B:
    //   ycl [n][25600][128] @52,428,800 ; b1cl @26,214,400
    //   h2p [n][4][6400][128] @0 ; w3a @26,214,400 (b1cl dead after wb2_wc1)
    unsigned short* ycl  = u + 52428800L;
    unsigned short* b1cl = u + 26214400L;
    unsigned short* h2p  = u;
    unsigned short* w3a  = u + 26214400L;

    // small-conv frag arena lives in d_out (conv3 overwrites all of d_out)
    unsigned short* wsa = (unsigned short*)d_out;
    unsigned short* a_conv1 = wsa;
    unsigned short* a_wc0   = wsa + 36 * 1024;
    unsigned short* a_wb1   = wsa + 44 * 1024;
    unsigned short* a_wb2   = wsa + 62 * 1024;
    unsigned short* a_wc1   = wsa + 80 * 1024;

    prep_small<<<dim3(24, 1, 1), dim3(256, 1, 1), 0, stream>>>(
        w1, wc0, wb1, wb2, wc1, w0, wsa);

    // STEM: conv0 + conv1 + wc0 fused -> ycl (round-12 geometry + prefetch)
    stem_fused<<<dim3(400, 1, 8), dim3(256, 1, 1), 0, stream>>>(
        x, a_conv1, a_wc0, b0, b1, bc0, ycl);

    // wb1: 3x3 s1 32->32 on x2 (ycl ch32-63, slot base 8) -> b1cl
    wb3x3<<<dim3(100, 1, 8), dim3(512, 1, 1), 0, stream>>>(
        ycl, 128, 8, a_wb1, bb1, b1cl);

    // wb2 (+resid) fused with wc1 -> h2p (bcl eliminated)
    wb2_wc1<<<dim3(100, 1, 8), dim3(512, 1, 1), 0, stream>>>(
        b1cl, ycl, a_wb2, a_wc1, bb2, bc1, h2p);

    // prep w3 fragments (b1cl now dead)
    prep_w3<<<dim3(36, 1, 1), dim3(256, 1, 1), 0, stream>>>(w3, w3a);

    conv3_one<<<dim3(25, 2, 8), dim3(512, 1, 1), 0, stream>>>(h2p, w3a, b3, (float*)d_out);
}

// Round 21
// 229.511 us; speedup vs baseline: 1.0781x; 1.0135x over previous
//
#include <hip/hip_runtime.h>
#include <hip/hip_bf16.h>

typedef __attribute__((ext_vector_type(8))) short short8;
typedef __attribute__((ext_vector_type(16))) float f32x16;
typedef __attribute__((ext_vector_type(4))) float f32x4;
typedef __attribute__((ext_vector_type(4))) unsigned int uint4v;
typedef __attribute__((ext_vector_type(4))) unsigned short ushort4v;

__device__ __forceinline__ float silu_f(float v) {
    return v * __builtin_amdgcn_rcpf(1.0f + __expf(-v));
}
__device__ __forceinline__ unsigned short bfhi(float v) {
    __hip_bfloat16 h = __float2bfloat16(v);
    return *reinterpret_cast<unsigned short*>(&h);
}
__device__ __forceinline__ float bf2f(unsigned short u) {
    __hip_bfloat16 h;
    *reinterpret_cast<unsigned short*>(&h) = u;
    return __bfloat162float(h);
}

// ======= weight prep (merged): f32 -> bf16 hi/lo fragments ==================
// blocks 0..23  -> small arena (d_out): conv1 @0 (36pf), wc0 @36, wb1 @44,
//                  wb2 @62, wc1 @80, w0 @92 (K=32 padded from 27). 94 pf.
// blocks 24..59 -> w3 arena (ws): pf = ((cg*9+tap)*4 + rr)*2+cc. 144 pf.
__global__ __launch_bounds__(256) void prep_all(
    const float* __restrict__ w1, const float* __restrict__ wc0,
    const float* __restrict__ wb1, const float* __restrict__ wb2,
    const float* __restrict__ wc1, const float* __restrict__ w0,
    const float* __restrict__ w3,
    unsigned short* __restrict__ arena, unsigned short* __restrict__ arena3)
{
    if (blockIdx.x < 24) {
        const int u = blockIdx.x * 256 + threadIdx.x;   // 0..6015
        if (u >= 6016) return;
        const int lane = u & 63, pf = u >> 6;
        float wv[8];
        if (pf < 36) {
            const int q = pf, cc = q & 1, rnd = (q >> 1) & 1, tap = q >> 2;
            const int co = cc * 32 + (lane & 31), ci0 = rnd * 16 + (lane >> 5) * 8;
            #pragma unroll
            for (int j = 0; j < 8; ++j) wv[j] = w1[(co * 32 + ci0 + j) * 9 + tap];
        } else if (pf < 44) {
            const int q = pf - 36, cc = q & 1, rnd = q >> 1;
            const int co = cc * 32 + (lane & 31), ci0 = rnd * 16 + (lane >> 5) * 8;
            #pragma unroll
            for (int j = 0; j < 8; ++j) wv[j] = wc0[co * 64 + ci0 + j];
        } else if (pf < 62) {
            const int q = pf - 44, rnd = q & 1, tap = q >> 1;
            const int co = lane & 31, ci0 = rnd * 16 + (lane >> 5) * 8;
            #pragma unroll
            for (int j = 0; j < 8; ++j) wv[j] = wb1[(co * 32 + ci0 + j) * 9 + tap];
        } else if (pf < 80) {
            const int q = pf - 62, rnd = q & 1, tap = q >> 1;
            const int co = lane & 31, ci0 = rnd * 16 + (lane >> 5) * 8;
            #pragma unroll
            for (int j = 0; j < 8; ++j) wv[j] = wb2[(co * 32 + ci0 + j) * 9 + tap];
        } else if (pf < 92) {
            const int q = pf - 80, cc = q & 1, rnd = q >> 1;
            const int co = cc * 32 + (lane & 31), ci0 = rnd * 16 + (lane >> 5) * 8;
            #pragma unroll
            for (int j = 0; j < 8; ++j) wv[j] = wc1[co * 96 + ci0 + j];
        } else {
            const int co = lane & 31;
            const int k0 = (pf - 92) * 16 + (lane >> 5) * 8;
            #pragma unroll
            for (int j = 0; j < 8; ++j) {
                const int k = k0 + j;
                wv[j] = (k < 27) ? w0[(co * 3 + k / 9) * 9 + (k % 9)] : 0.0f;
            }
        }
        unsigned short hs[8], ls[8];
        #pragma unroll
        for (int j = 0; j < 8; ++j) {
            unsigned short hh = bfhi(wv[j]);
            hs[j] = hh; ls[j] = bfhi(wv[j] - bf2f(hh));
        }
        *reinterpret_cast<short8*>(&arena[pf * 1024 + lane * 8])       = *(short8*)hs;
        *reinterpret_cast<short8*>(&arena[pf * 1024 + 512 + lane * 8]) = *(short8*)ls;
    } else {
        const int u = (blockIdx.x - 24) * 256 + threadIdx.x;   // 0..9215
        const int lane = u & 63, pf = u >> 6;
        const int cc = pf & 1, rr = (pf >> 1) & 3, t9 = pf >> 3;
        const int tap = t9 % 9, cg = t9 / 9;
        const int co = cg * 64 + cc * 32 + (lane & 31);
        const int ci0 = rr * 16 + (lane >> 5) * 8;
        unsigned short hs[8], ls[8];
        #pragma unroll
        for (int j = 0; j < 8; ++j) {
            float wv = w3[(co * 64 + ci0 + j) * 9 + tap];
            unsigned short hh = bfhi(wv);
            hs[j] = hh; ls[j] = bfhi(wv - bf2f(hh));
        }
        *reinterpret_cast<short8*>(&arena3[pf * 1024 + lane * 8])       = *(short8*)hs;
        *reinterpret_cast<short8*>(&arena3[pf * 1024 + 512 + lane * 8]) = *(short8*)ls;
    }
}

// ---- stem phase-A helpers (325-rec 32x2 geometry, round-12/15 proven) -----
struct GDesc {
    int rc, Bsafe, Y, X;
    bool validR, valid, fastw;
};

__device__ __forceinline__ GDesc stem_desc(int g, int p, int ox0, int oy0) {
    GDesc d;
    d.rc = g * 32 + p;
    d.validR = d.rc < 325;
    const int rec_c = d.validR ? d.rc : 324;
    int gp, row, col;
    if (rec_c < 64)       { gp = 0; row = rec_c >> 5; col = rec_c & 31; }
    else if (rec_c < 130) { gp = 1; int r2 = rec_c - 64;  row = r2 / 33; col = r2 - row * 33; }
    else if (rec_c < 226) { gp = 2; int r2 = rec_c - 130; row = r2 >> 5; col = r2 & 31; }
    else                  { gp = 3; int r2 = rec_c - 226; row = r2 / 33; col = r2 - row * 33; }
    const int gr = (gp >= 2) ? oy0 - 1 + row : oy0 + row;
    const int gc = (gp & 1)  ? ox0 - 1 + col : ox0 + col;
    d.valid = d.validR && ((unsigned)gr < 160u) && ((unsigned)gc < 160u);
    d.Y = 2 * gr + (gp >> 1);
    d.X = 2 * gc + (gp & 1);
    d.Bsafe = d.valid ? (1280 * d.Y + 2 * d.X) : 641;
    const bool interior = d.valid && gr > 0 && gr < 159 && gc > 0 && gc < 159;
    d.fastw = __all(interior);
    return d;
}

__device__ __forceinline__ void stem_issue(
    int Bsafe, const int* doff, const float* __restrict__ xb, float* xv)
{
    #pragma unroll
    for (int idx = 0; idx < 16; ++idx) {
        int a = Bsafe + doff[idx];
        a = max(a, 0);
        a = min(a, 1228799);
        xv[idx] = xb[a];
    }
}

__device__ __forceinline__ void stem_process(
    const GDesc& d, const float* xv, unsigned short* lds,
    const unsigned short* __restrict__ wfr, const float* __restrict__ b0,
    int h, int h8, int lane)
{
    f32x16 a0;
    #pragma unroll
    for (int q = 0; q < 4; ++q) {
        f32x4 b4 = *reinterpret_cast<const f32x4*>(&b0[q * 8 + 4 * h]);
        #pragma unroll
        for (int r2 = 0; r2 < 4; ++r2) a0[q * 4 + r2] = b4[r2];
    }

    #pragma unroll
    for (int rnd = 0; rnd < 2; ++rnd) {
        unsigned short hs[8], ls[8];
        if (d.fastw) {
            #pragma unroll
            for (int j = 0; j < 8; ++j) {
                float v = xv[rnd * 8 + j];
                if (rnd == 1 && j >= 3) v = (h == 0) ? v : 0.0f;
                unsigned short hh = bfhi(v);
                hs[j] = hh; ls[j] = bfhi(v - bf2f(hh));
            }
        } else {
            #pragma unroll
            for (int j = 0; j < 8; ++j) {
                const int k = rnd * 16 + h8 + j;
                const int ci = (k * 57) >> 9;
                const int tap = k - 9 * ci;
                const int dy = (tap * 11) >> 5, dx = tap - 3 * dy;
                const int iy = 2 * d.Y + dy - 1;
                const int ix = 2 * d.X + dx - 1;
                bool ok = d.valid && ((unsigned)iy < 640u) && ((unsigned)ix < 640u);
                if (rnd == 1 && j >= 3) ok = ok && (h == 0);
                float v = ok ? xv[rnd * 8 + j] : 0.0f;
                unsigned short hh = bfhi(v);
                hs[j] = hh; ls[j] = bfhi(v - bf2f(hh));
            }
        }
        short8 Bh = *(short8*)hs, Bl = *(short8*)ls;
        const unsigned short* fb = wfr + (92 + rnd) * 1024 + lane * 8;
        short8 Awh = *reinterpret_cast<const short8*>(fb);
        short8 Awl = *reinterpret_cast<const short8*>(fb + 512);
        a0 = __builtin_amdgcn_mfma_f32_32x32x16_bf16(Awh, Bh, a0, 0, 0, 0);
        a0 = __builtin_amdgcn_mfma_f32_32x32x16_bf16(Awh, Bl, a0, 0, 0, 0);
        a0 = __builtin_amdgcn_mfma_f32_32x32x16_bf16(Awl, Bh, a0, 0, 0, 0);
    }

    if (d.validR) {
        const int pm = d.rc & 7;
        #pragma unroll
        for (int q = 0; q < 4; ++q) {
            ushort4v hv, lv;
            #pragma unroll
            for (int r2 = 0; r2 < 4; ++r2) {
                float v = d.valid ? silu_f(a0[q * 4 + r2]) : 0.0f;
                unsigned short hh = bfhi(v);
                hv[r2] = hh; lv[r2] = bfhi(v - bf2f(hh));
            }
            *reinterpret_cast<ushort4v*>(&lds[d.rc * 64 + (((2 * q)     ^ pm) * 8) + 4 * h]) = hv;
            *reinterpret_cast<ushort4v*>(&lds[d.rc * 64 + (((2 * q + 1) ^ pm) * 8) + 4 * h]) = lv;
        }
    }
}

// ============ STEM: conv0 (3->32 s2) + conv1 (32->64 s2 3x3) + wc0 (1x1) ====
// Round-12 geometry (256 thr, 32x2 tile); phase A with depth-1 prefetch.
__global__ __launch_bounds__(256, 4) void stem_fused(
    const float* __restrict__ x, const unsigned short* __restrict__ wfr,
    const unsigned short* __restrict__ wc0fr, const float* __restrict__ b0,
    const float* __restrict__ bias, const float* __restrict__ bc0,
    unsigned short* __restrict__ ycl)
{
    __shared__ unsigned short lds[20800];        // 325 recs x 64 ush = 41.6 KB
    const int tid = threadIdx.x;
    const int wv = tid >> 6, lane = tid & 63;
    const int p = lane & 31, h = lane >> 5;
    const int r = wv >> 1, cc = wv & 1;
    const int bx = blockIdx.x % 5, by = blockIdx.x / 5;
    const int ox0 = bx * 32, oy0 = by * 2;
    const int n = blockIdx.z;
    const float* xb = x + (long)n * 1228800;

    const int h8 = h * 8;
    int doff[16];
    #pragma unroll
    for (int idx = 0; idx < 16; ++idx) {
        const int k = (idx >> 3) * 16 + h8 + (idx & 7);
        if (k < 27) {
            const int ci = (k * 57) >> 9;
            const int tap = k - 9 * ci;
            const int dy = (tap * 11) >> 5, dx = tap - 3 * dy;
            doff[idx] = ci * 409600 + (dy - 1) * 640 + (dx - 1);
        } else {
            doff[idx] = 0;
        }
    }

    // ---- phase A with depth-1 prefetch: groups wv, wv+4, (wv+8 if wv<3)
    {
        GDesc d0 = stem_desc(wv, p, ox0, oy0);
        float xva[16];
        stem_issue(d0.Bsafe, doff, xb, xva);

        GDesc d1 = stem_desc(wv + 4, p, ox0, oy0);
        float xvb[16];
        stem_issue(d1.Bsafe, doff, xb, xvb);

        stem_process(d0, xva, lds, wfr, b0, h, h8, lane);

        if (wv < 3) {
            GDesc d2 = stem_desc(wv + 8, p, ox0, oy0);
            stem_issue(d2.Bsafe, doff, xb, xva);
            stem_process(d1, xvb, lds, wfr, b0, h, h8, lane);
            stem_process(d2, xva, lds, wfr, b0, h, h8, lane);
        } else {
            stem_process(d1, xvb, lds, wfr, b0, h, h8, lane);
        }
    }
    __syncthreads();

    // ---- conv1 K-loop from LDS h0 tile (no staging, no barriers)
    f32x16 acc;
    #pragma unroll
    for (int q = 0; q < 4; ++q) {
        f32x4 b4 = *reinterpret_cast<const f32x4*>(&bias[cc * 32 + q * 8 + 4 * h]);
        #pragma unroll
        for (int r2 = 0; r2 < 4; ++r2) acc[q * 4 + r2] = b4[r2];
    }
    #pragma unroll
    for (int c = 0; c < 2; ++c) {
        #pragma unroll
        for (int tap = 0; tap < 9; ++tap) {
            const int dy = tap / 3 - 1, dx = tap % 3 - 1;
            const int ppy = dy & 1, ppx = dx & 1;
            const int toy = ppy ? ((dy == -1) ? 0 : 1) : 0;
            const int tox = ppx ? ((dx == -1) ? 0 : 1) : 0;
            const int gp = ppy * 2 + ppx;
            const int base = (gp == 0) ? 0 : (gp == 1) ? 64 : (gp == 2) ? 130 : 226;
            const int W = ppx ? 33 : 32;
            const int rec = base + (ppy ? (r + toy) : r) * W + (p + tox);
            const unsigned short* t = &lds[rec * 64];
            const int pm = rec & 7;
            short8 Bh = *reinterpret_cast<const short8*>(t + (((4 * c + 2 * h)     ^ pm) * 8));
            short8 Bl = *reinterpret_cast<const short8*>(t + (((4 * c + 2 * h + 1) ^ pm) * 8));
            const unsigned short* fb = wfr + ((tap * 2 + c) * 2 + cc) * 1024 + lane * 8;
            short8 Awh = *reinterpret_cast<const short8*>(fb);
            short8 Awl = *reinterpret_cast<const short8*>(fb + 512);
            acc = __builtin_amdgcn_mfma_f32_32x32x16_bf16(Awh, Bh, acc, 0, 0, 0);
            acc = __builtin_amdgcn_mfma_f32_32x32x16_bf16(Awh, Bl, acc, 0, 0, 0);
            acc = __builtin_amdgcn_mfma_f32_32x32x16_bf16(Awl, Bh, acc, 0, 0, 0);
        }
    }

    // ---- stage y = silu(conv1) to LDS (64 recs x 128 ush), aliases h0 tile
    __syncthreads();
    {
        const int rec2 = r * 32 + p;
        #pragma unroll
        for (int q = 0; q < 4; ++q) {
            ushort4v hv, lv;
            #pragma unroll
            for (int r2 = 0; r2 < 4; ++r2) {
                float v = silu_f(acc[q * 4 + r2]);
                unsigned short hh = bfhi(v);
                hv[r2] = hh; lv[r2] = bfhi(v - bf2f(hh));
            }
            const int lsh = (2 * (cc * 4 + q))     ^ (rec2 & 15);
            const int lsl = (2 * (cc * 4 + q) + 1) ^ (rec2 & 15);
            *reinterpret_cast<ushort4v*>(&lds[rec2 * 128 + lsh * 8 + 4 * h]) = hv;
            *reinterpret_cast<ushort4v*>(&lds[rec2 * 128 + lsl * 8 + 4 * h]) = lv;
        }
    }
    __syncthreads();

    // ---- wc0: 1x1 64->64 from LDS y-tile; wave owns cc output chunk
    f32x16 a2;
    #pragma unroll
    for (int q = 0; q < 4; ++q) {
        f32x4 b4 = *reinterpret_cast<const f32x4*>(&bc0[cc * 32 + q * 8 + 4 * h]);
        #pragma unroll
        for (int r2 = 0; r2 < 4; ++r2) a2[q * 4 + r2] = b4[r2];
    }
    {
        const int rec2 = r * 32 + p;
        #pragma unroll
        for (int rnd = 0; rnd < 4; ++rnd) {
            const int sh = (4 * rnd + 2 * h)     ^ (rec2 & 15);
            const int sl = (4 * rnd + 2 * h + 1) ^ (rec2 & 15);
            short8 Bh = *reinterpret_cast<const short8*>(&lds[rec2 * 128 + sh * 8]);
            short8 Bl = *reinterpret_cast<const short8*>(&lds[rec2 * 128 + sl * 8]);
            const unsigned short* fb = wc0fr + (rnd * 2 + cc) * 1024 + lane * 8;
            short8 Awh = *reinterpret_cast<const short8*>(fb);
            short8 Awl = *reinterpret_cast<const short8*>(fb + 512);
            a2 = __builtin_amdgcn_mfma_f32_32x32x16_bf16(Awh, Bh, a2, 0, 0, 0);
            a2 = __builtin_amdgcn_mfma_f32_32x32x16_bf16(Awh, Bl, a2, 0, 0, 0);
            a2 = __builtin_amdgcn_mfma_f32_32x32x16_bf16(Awl, Bh, a2, 0, 0, 0);
        }
    }

    const int oy = oy0 + r;
    unsigned short* op = ycl + ((long)n * 25600 + (long)oy * 160 + ox0 + p) * 128;
    #pragma unroll
    for (int q = 0; q < 4; ++q) {
        ushort4v hv, lv;
        #pragma unroll
        for (int r2 = 0; r2 < 4; ++r2) {
            float v = silu_f(a2[q * 4 + r2]);
            unsigned short hh = bfhi(v);
            hv[r2] = hh; lv[r2] = bfhi(v - bf2f(hh));
        }
        const int gq = cc * 4 + q;
        *reinterpret_cast<ushort4v*>(op + gq * 16 + 4 * h)     = hv;
        *reinterpret_cast<ushort4v*>(op + gq * 16 + 8 + 4 * h) = lv;
    }
}

// ============ wb1: 32->32 s1 3x3, tile-only LDS, frags from global ==========
__global__ __launch_bounds__(512, 4) void wb3x3(
    const unsigned short* __restrict__ in, int inRec, int inSlot0,
    const unsigned short* __restrict__ wfr, const float* __restrict__ bias,
    unsigned short* __restrict__ outb)
{
    __shared__ unsigned short lds[21760];        // tile 34x10 x 64 ush (43.5 KB)
    const int tid = threadIdx.x;
    const int wv = tid >> 6, lane = tid & 63;
    const int p = lane & 31, h = lane >> 5;
    const int bx = blockIdx.x % 5, by = blockIdx.x / 5;
    const int ox0 = bx * 32, oy0 = by * 8;
    const int n = blockIdx.z;

    for (int u = tid; u < 2720; u += 512) {      // tile 34x10, 8 slots/rec
        const int rec = u >> 3, s = u & 7;
        const int row = rec / 34, col = rec - row * 34;
        const int gr = oy0 - 1 + row, gc = ox0 - 1 + col;
        uint4v val = {0, 0, 0, 0};
        if (gr >= 0 && gr < 160 && gc >= 0 && gc < 160)
            val = *reinterpret_cast<const uint4v*>(
                in + ((long)n * 25600 + gr * 160 + gc) * inRec + (inSlot0 + s) * 8);
        *reinterpret_cast<uint4v*>(&lds[rec * 64 + ((s ^ (rec & 7)) * 8)]) = val;
    }

    f32x16 acc;
    #pragma unroll
    for (int q = 0; q < 4; ++q) {
        f32x4 b4 = *reinterpret_cast<const f32x4*>(&bias[q * 8 + 4 * h]);
        #pragma unroll
        for (int r = 0; r < 4; ++r) acc[q * 4 + r] = b4[r];
    }
    __syncthreads();

    #pragma unroll
    for (int tap = 0; tap < 9; ++tap) {
        const int dy = tap / 3 - 1, dx = tap % 3 - 1;
        const int rec = (wv + dy + 1) * 34 + (p + dx + 1);
        const unsigned short* t = &lds[rec * 64];
        short8 Bh[2], Bl[2];
        #pragma unroll
        for (int rnd = 0; rnd < 2; ++rnd) {
            Bh[rnd] = *reinterpret_cast<const short8*>(t + (((rnd*4 + 2*h)     ^ (rec & 7)) * 8));
            Bl[rnd] = *reinterpret_cast<const short8*>(t + (((rnd*4 + 2*h + 1) ^ (rec & 7)) * 8));
        }
        #pragma unroll
        for (int rnd = 0; rnd < 2; ++rnd) {
            const unsigned short* fb = wfr + (tap * 2 + rnd) * 1024 + lane * 8;
            short8 Awh = *reinterpret_cast<const short8*>(fb);
            short8 Awl = *reinterpret_cast<const short8*>(fb + 512);
            acc = __builtin_amdgcn_mfma_f32_32x32x16_bf16(Awh, Bh[rnd], acc, 0, 0, 0);
            acc = __builtin_amdgcn_mfma_f32_32x32x16_bf16(Awh, Bl[rnd], acc, 0, 0, 0);
            acc = __builtin_amdgcn_mfma_f32_32x32x16_bf16(Awl, Bh[rnd], acc, 0, 0, 0);
        }
    }

    const int oy = oy0 + wv;
    const long prow = (long)n * 25600 + (long)oy * 160 + ox0 + p;
    unsigned short* op = outb + prow * 64;
    #pragma unroll
    for (int q = 0; q < 4; ++q) {
        ushort4v hv, lv;
        #pragma unroll
        for (int r = 0; r < 4; ++r) {
            float v = silu_f(acc[q * 4 + r]);
            unsigned short hh = bfhi(v);
            hv[r] = hh; lv[r] = bfhi(v - bf2f(hh));
        }
        *reinterpret_cast<ushort4v*>(op + q * 16 + 4 * h)     = hv;
        *reinterpret_cast<ushort4v*>(op + q * 16 + 8 + 4 * h) = lv;
    }
}

// ============ wb2+wc1 FUSED: 3x3 32->32 (+resid) then 1x1 96->64 ============
// wb2's b-tile (32x8 px) goes to LDS (no bcl round-trip); wc1 reads ycl from
// global (4 rnds) + b from LDS (2 rnds); writes h2p parity-split.
__global__ __launch_bounds__(512, 4) void wb2_wc1(
    const unsigned short* __restrict__ b1cl, const unsigned short* __restrict__ ycl,
    const unsigned short* __restrict__ wfr2, const unsigned short* __restrict__ wfrc,
    const float* __restrict__ bb2, const float* __restrict__ bc1,
    unsigned short* __restrict__ h2p)
{
    __shared__ unsigned short lds[21760];        // 34x10 tile / 256x64 b-tile
    const int tid = threadIdx.x;
    const int wv = tid >> 6, lane = tid & 63;
    const int p = lane & 31, h = lane >> 5;
    const int bx = blockIdx.x % 5, by = blockIdx.x / 5;
    const int ox0 = bx * 32, oy0 = by * 8;
    const int n = blockIdx.z;

    // ---- stage b1cl tile 34x10 (8 slots/rec)
    for (int u = tid; u < 2720; u += 512) {
        const int rec = u >> 3, s = u & 7;
        const int row = rec / 34, col = rec - row * 34;
        const int gr = oy0 - 1 + row, gc = ox0 - 1 + col;
        uint4v val = {0, 0, 0, 0};
        if (gr >= 0 && gr < 160 && gc >= 0 && gc < 160)
            val = *reinterpret_cast<const uint4v*>(
                b1cl + ((long)n * 25600 + gr * 160 + gc) * 64 + s * 8);
        *reinterpret_cast<uint4v*>(&lds[rec * 64 + ((s ^ (rec & 7)) * 8)]) = val;
    }

    f32x16 acc;
    #pragma unroll
    for (int q = 0; q < 4; ++q) {
        f32x4 b4 = *reinterpret_cast<const f32x4*>(&bb2[q * 8 + 4 * h]);
        #pragma unroll
        for (int r = 0; r < 4; ++r) acc[q * 4 + r] = b4[r];
    }
    __syncthreads();

    // ---- wb2 K-loop (9 taps x 2 rnds)
    #pragma unroll
    for (int tap = 0; tap < 9; ++tap) {
        const int dy = tap / 3 - 1, dx = tap % 3 - 1;
        const int rec = (wv + dy + 1) * 34 + (p + dx + 1);
        const unsigned short* t = &lds[rec * 64];
        short8 Bh[2], Bl[2];
        #pragma unroll
        for (int rnd = 0; rnd < 2; ++rnd) {
            Bh[rnd] = *reinterpret_cast<const short8*>(t + (((rnd*4 + 2*h)     ^ (rec & 7)) * 8));
            Bl[rnd] = *reinterpret_cast<const short8*>(t + (((rnd*4 + 2*h + 1) ^ (rec & 7)) * 8));
        }
        #pragma unroll
        for (int rnd = 0; rnd < 2; ++rnd) {
            const unsigned short* fb = wfr2 + (tap * 2 + rnd) * 1024 + lane * 8;
            short8 Awh = *reinterpret_cast<const short8*>(fb);
            short8 Awl = *reinterpret_cast<const short8*>(fb + 512);
            acc = __builtin_amdgcn_mfma_f32_32x32x16_bf16(Awh, Bh[rnd], acc, 0, 0, 0);
            acc = __builtin_amdgcn_mfma_f32_32x32x16_bf16(Awh, Bl[rnd], acc, 0, 0, 0);
            acc = __builtin_amdgcn_mfma_f32_32x32x16_bf16(Awl, Bh[rnd], acc, 0, 0, 0);
        }
    }

    // ---- b = silu(wb2) + x2(ycl ch32-63); compute in regs
    const int oy = oy0 + wv;
    const long prow = (long)n * 25600 + (long)oy * 160 + ox0 + p;
    const unsigned short* rp = ycl + prow * 128;
    float vs[16];
    #pragma unroll
    for (int q = 0; q < 4; ++q) {
        ushort4v rh = *reinterpret_cast<const ushort4v*>(rp + (q + 4) * 16 + 4 * h);
        ushort4v rl = *reinterpret_cast<const ushort4v*>(rp + (q + 4) * 16 + 8 + 4 * h);
        #pragma unroll
        for (int r = 0; r < 4; ++r)
            vs[q * 4 + r] = silu_f(acc[q * 4 + r]) + bf2f(rh[r]) + bf2f(rl[r]);
    }

    // ---- write b-tile to LDS (256 recs x 64 ush), aliases input tile
    __syncthreads();
    {
        const int rec = wv * 32 + p;
        const int pm = rec & 7;
        #pragma unroll
        for (int q = 0; q < 4; ++q) {
            ushort4v hv, lv;
            #pragma unroll
            for (int r = 0; r < 4; ++r) {
                unsigned short hh = bfhi(vs[q * 4 + r]);
                hv[r] = hh; lv[r] = bfhi(vs[q * 4 + r] - bf2f(hh));
            }
            *reinterpret_cast<ushort4v*>(&lds[rec * 64 + (((2 * q)     ^ pm) * 8) + 4 * h]) = hv;
            *reinterpret_cast<ushort4v*>(&lds[rec * 64 + (((2 * q + 1) ^ pm) * 8) + 4 * h]) = lv;
        }
    }
    __syncthreads();

    // ---- wc1 phase: wave = (row-group wv>>1, cc=wv&1); 2 row-groups per wave
    const int cc = wv & 1;
    #pragma unroll
    for (int g2 = 0; g2 < 2; ++g2) {
        const int rowg = (wv >> 1) + g2 * 4;
        const int oyg = oy0 + rowg;
        const long pg = (long)n * 25600 + (long)oyg * 160 + ox0 + p;

        f32x16 a2;
        #pragma unroll
        for (int q = 0; q < 4; ++q) {
            f32x4 b4 = *reinterpret_cast<const f32x4*>(&bc1[cc * 32 + q * 8 + 4 * h]);
            #pragma unroll
            for (int r = 0; r < 4; ++r) a2[q * 4 + r] = b4[r];
        }

        // 4 rnds from ycl (ch 0-63)
        #pragma unroll
        for (int rnd = 0; rnd < 4; ++rnd) {
            const unsigned short* sp = ycl + pg * 128 + (rnd * 4 + 2 * h) * 8;
            short8 Bh = *reinterpret_cast<const short8*>(sp);
            short8 Bl = *reinterpret_cast<const short8*>(sp + 8);
            const unsigned short* fb = wfrc + (rnd * 2 + cc) * 1024 + lane * 8;
            short8 Awh = *reinterpret_cast<const short8*>(fb);
            short8 Awl = *reinterpret_cast<const short8*>(fb + 512);
            a2 = __builtin_amdgcn_mfma_f32_32x32x16_bf16(Awh, Bh, a2, 0, 0, 0);
            a2 = __builtin_amdgcn_mfma_f32_32x32x16_bf16(Awh, Bl, a2, 0, 0, 0);
            a2 = __builtin_amdgcn_mfma_f32_32x32x16_bf16(Awl, Bh, a2, 0, 0, 0);
        }
        // 2 rnds from LDS b-tile (ch 64-95)
        const int recb = rowg * 32 + p;
        const int pmb = recb & 7;
        #pragma unroll
        for (int rnd = 0; rnd < 2; ++rnd) {
            const unsigned short* t = &lds[recb * 64];
            short8 Bh = *reinterpret_cast<const short8*>(t + (((4*rnd + 2*h)     ^ pmb) * 8));
            short8 Bl = *reinterpret_cast<const short8*>(t + (((4*rnd + 2*h + 1) ^ pmb) * 8));
            const unsigned short* fb = wfrc + ((4 + rnd) * 2 + cc) * 1024 + lane * 8;
            short8 Awh = *reinterpret_cast<const short8*>(fb);
            short8 Awl = *reinterpret_cast<const short8*>(fb + 512);
            a2 = __builtin_amdgcn_mfma_f32_32x32x16_bf16(Awh, Bh, a2, 0, 0, 0);
            a2 = __builtin_amdgcn_mfma_f32_32x32x16_bf16(Awh, Bl, a2, 0, 0, 0);
            a2 = __builtin_amdgcn_mfma_f32_32x32x16_bf16(Awl, Bh, a2, 0, 0, 0);
        }

        // write h2p parity-split
        const int xx = ox0 + p;
        const int pl = (oyg & 1) * 2 + (xx & 1);
        unsigned short* op = h2p + (((long)n * 4 + pl) * 6400 + (oyg >> 1) * 80 + (xx >> 1)) * 128;
        #pragma unroll
        for (int q = 0; q < 4; ++q) {
            ushort4v hv, lv;
            #pragma unroll
            for (int r = 0; r < 4; ++r) {
                float v = silu_f(a2[q * 4 + r]);
                unsigned short hh = bfhi(v);
                hv[r] = hh; lv[r] = bfhi(v - bf2f(hh));
            }
            const int gq = cc * 4 + q;
            *reinterpret_cast<ushort4v*>(op + gq * 16 + 4 * h)     = hv;
            *reinterpret_cast<ushort4v*>(op + gq * 16 + 8 + 4 * h) = lv;
        }
    }
}

// ============ conv3: 64->128 s2 3x3, SINGLE kernel, 4 staging rounds ========
__global__ __launch_bounds__(512, 4) void conv3_one(
    const unsigned short* __restrict__ h2p, const unsigned short* __restrict__ wfr,
    const float* __restrict__ bias, float* __restrict__ outf)
{
    __shared__ unsigned short lds[34848];        // tile 1089 x 32 ush (69.7 KB)
    const int tid = threadIdx.x;
    const int wv = tid >> 6, lane = tid & 63;
    const int p = lane & 31, h = lane >> 5;
    const int bx = blockIdx.x % 5, by = blockIdx.x / 5;
    const int ox0 = bx * 16, oy0 = by * 16;
    const int cg = blockIdx.y;
    const int co0 = cg * 64;
    const int n = blockIdx.z;

    f32x16 acc[2];
    #pragma unroll
    for (int cc = 0; cc < 2; ++cc)
        #pragma unroll
        for (int q = 0; q < 4; ++q) {
            f32x4 b4 = *reinterpret_cast<const f32x4*>(&bias[co0 + cc * 32 + q * 8 + 4 * h]);
            #pragma unroll
            for (int r = 0; r < 4; ++r) acc[cc][q * 4 + r] = b4[r];
        }

    for (int rr = 0; rr < 4; ++rr) {
        __syncthreads();
        for (int u = tid; u < 4356; u += 512) {
            const int rec = u >> 2, s = u & 3;
            int gp, row, col;
            if (rec < 256)      { gp = 0; row = rec >> 4; col = rec & 15; }
            else if (rec < 528) { gp = 1; int r2 = rec - 256; row = r2 / 17; col = r2 - row * 17; }
            else if (rec < 800) { gp = 2; int r2 = rec - 528; row = r2 >> 4; col = r2 & 15; }
            else                { gp = 3; int r2 = rec - 800; row = r2 / 17; col = r2 - row * 17; }
            const int gr = (gp >= 2) ? oy0 - 1 + row : oy0 + row;
            const int gc = (gp & 1)  ? ox0 - 1 + col : ox0 + col;
            uint4v val = {0, 0, 0, 0};
            if (gr >= 0 && gr < 80 && gc >= 0 && gc < 80)
                val = *reinterpret_cast<const uint4v*>(
                    h2p + (((long)n * 4 + gp) * 6400 + gr * 80 + gc) * 128 + (rr * 4 + s) * 8);
            *reinterpret_cast<uint4v*>(&lds[rec * 32 + ((s ^ ((rec >> 1) & 3)) * 8)]) = val;
        }
        __syncthreads();

        #pragma unroll
        for (int tap = 0; tap < 9; ++tap) {
            const int dy = tap / 3 - 1, dx = tap % 3 - 1;
            const int ppy = dy & 1, ppx = dx & 1;
            const int toy = ppy ? ((dy == -1) ? 0 : 1) : 0;
            const int tox = ppx ? ((dx == -1) ? 0 : 1) : 0;
            const int gp = ppy * 2 + ppx;
            const int base = (gp == 0) ? 0 : (gp == 1) ? 256 : (gp == 2) ? 528 : 800;
            const int W = ppx ? 17 : 16;
            const int rl = wv * 2 + (p >> 4), cl = p & 15;
            const int rec = base + (ppy ? (rl + toy) : rl) * W + (cl + tox);
            const unsigned short* t = &lds[rec * 32];
            const int pm = (rec >> 1) & 3;
            short8 Bh = *reinterpret_cast<const short8*>(t + (((2*h)     ^ pm) * 8));
            short8 Bl = *reinterpret_cast<const short8*>(t + (((2*h + 1) ^ pm) * 8));
            #pragma unroll
            for (int cc = 0; cc < 2; ++cc) {
                const unsigned short* fb =
                    wfr + (((cg * 9 + tap) * 4 + rr) * 2 + cc) * 1024 + lane * 8;
                short8 Awh = *reinterpret_cast<const short8*>(fb);
                short8 Awl = *reinterpret_cast<const short8*>(fb + 512);
                acc[cc] = __builtin_amdgcn_mfma_f32_32x32x16_bf16(Awh, Bh, acc[cc], 0, 0, 0);
                acc[cc] = __builtin_amdgcn_mfma_f32_32x32x16_bf16(Awh, Bl, acc[cc], 0, 0, 0);
                acc[cc] = __builtin_amdgcn_mfma_f32_32x32x16_bf16(Awl, Bh, acc[cc], 0, 0, 0);
            }
        }
    }

    const int rl = wv * 2 + (p >> 4);
    const int oy = oy0 + rl;
    const int pxg = oy * 80 + ox0 + (p & 15);
    #pragma unroll
    for (int cc = 0; cc < 2; ++cc)
        #pragma unroll
        for (int q = 0; q < 4; ++q)
            #pragma unroll
            for (int r = 0; r < 4; ++r) {
                const int co = co0 + cc * 32 + q * 8 + 4 * h + r;
                outf[((long)n * 128 + co) * 6400 + pxg] = silu_f(acc[cc][q * 4 + r]);
            }
}

extern "C" void kernel_launch(void* const* d_in, const int* in_sizes, int n_in,
                              void* d_out, int out_size, void* d_ws, size_t ws_size,
                              hipStream_t stream) {
    const float* x   = (const float*)d_in[0];
    const float* w0  = (const float*)d_in[1];
    const float* b0  = (const float*)d_in[2];
    const float* w1  = (const float*)d_in[3];
    const float* b1  = (const float*)d_in[4];
    const float* wc0 = (const float*)d_in[5];
    const float* bc0 = (const float*)d_in[6];
    const float* wb1 = (const float*)d_in[7];
    const float* bb1 = (const float*)d_in[8];
    const float* wb2 = (const float*)d_in[9];
    const float* bb2 = (const float*)d_in[10];
    const float* wc1 = (const float*)d_in[11];
    const float* bc1 = (const float*)d_in[12];
    const float* w3  = (const float*)d_in[13];
    const float* b3  = (const float*)d_in[14];

    unsigned short* u = (unsigned short*)d_ws;
    // ws (ushort offsets), peak 157,286,400 B:
    //   ycl [n][25600][128] @52,428,800 ; b1cl @26,214,400
    //   h2p [n][4][6400][128] @0 ; w3a @39,321,600 (never-conflicting slot)
    unsigned short* ycl  = u + 52428800L;
    unsigned short* b1cl = u + 26214400L;
    unsigned short* h2p  = u;
    unsigned short* w3a  = u + 39321600L;

    // small-conv frag arena lives in d_out (conv3 overwrites all of d_out)
    unsigned short* wsa = (unsigned short*)d_out;
    unsigned short* a_conv1 = wsa;
    unsigned short* a_wc0   = wsa + 36 * 1024;
    unsigned short* a_wb1   = wsa + 44 * 1024;
    unsigned short* a_wb2   = wsa + 62 * 1024;
    unsigned short* a_wc1   = wsa + 80 * 1024;

    // merged weight prep (small arena + w3 arena) in one dispatch
    prep_all<<<dim3(60, 1, 1), dim3(256, 1, 1), 0, stream>>>(
        w1, wc0, wb1, wb2, wc1, w0, w3, wsa, w3a);

    // STEM: conv0 + conv1 + wc0 fused -> ycl (round-12 geometry + prefetch)
    stem_fused<<<dim3(400, 1, 8), dim3(256, 1, 1), 0, stream>>>(
        x, a_conv1, a_wc0, b0, b1, bc0, ycl);

    // wb1: 3x3 s1 32->32 on x2 (ycl ch32-63, slot base 8) -> b1cl
    wb3x3<<<dim3(100, 1, 8), dim3(512, 1, 1), 0, stream>>>(
        ycl, 128, 8, a_wb1, bb1, b1cl);

    // wb2 (+resid) fused with wc1 -> h2p (bcl eliminated)
    wb2_wc1<<<dim3(100, 1, 8), dim3(512, 1, 1), 0, stream>>>(
        b1cl, ycl, a_wb2, a_wc1, bb2, bc1, h2p);

    conv3_one<<<dim3(25, 2, 8), dim3(512, 1, 1), 0, stream>>>(h2p, w3a, b3, (float*)d_out);
}